// Round 14
// baseline (495.668 us; speedup 1.0000x reference)
//
#include <hip/hip_runtime.h>
#include <hip/hip_bf16.h>
#include <math.h>

#define NB 8
#define TT 2048
#define SS 2048
#define CC 1024
#define EE 1024
#define NMAX 1280

typedef __attribute__((ext_vector_type(8))) short short8;
typedef __attribute__((ext_vector_type(4))) float f32x4;

__device__ __forceinline__ unsigned short f2bf(float f) {
  unsigned u = __builtin_bit_cast(unsigned, f);
  u += 0x7fffu + ((u >> 16) & 1u);          // RNE
  return (unsigned short)(u >> 16);
}
__device__ __forceinline__ float bf2f(unsigned short h) {
  unsigned u = ((unsigned)h) << 16;
  return __builtin_bit_cast(float, u);
}
__device__ __forceinline__ void gload16(const void* g, void* l) {
  __builtin_amdgcn_global_load_lds((const __attribute__((address_space(1))) void*)g,
                                   (__attribute__((address_space(3))) void*)l, 16, 0, 0);
}
__device__ __forceinline__ unsigned ldsoff(const void* p) {
  return (unsigned)(size_t)(const __attribute__((address_space(3))) char*)p;
}
__device__ __forceinline__ short8 ds128(unsigned off) {
  short8 r;
  asm volatile("ds_read_b128 %0, %1" : "=v"(r) : "v"(off));
  return r;
}
// XOR swizzle: bits 4-6 ^= bits 7-9 (involution)
__device__ __forceinline__ int swzi(int x) { return x ^ (((x >> 7) & 7) << 4); }

#define WAITV(N) asm volatile("s_waitcnt vmcnt(" #N ")" ::: "memory")
#define WAITL(N) asm volatile("s_waitcnt lgkmcnt(" #N ")" ::: "memory")
#define BAR() __builtin_amdgcn_s_barrier()
#define SCH0() __builtin_amdgcn_sched_barrier(0)
#define PRIO1() __builtin_amdgcn_s_setprio(1)
#define PRIO0() __builtin_amdgcn_s_setprio(0)
#define MF(a_, b_, c_) __builtin_amdgcn_mfma_f32_16x16x32_bf16(a_, b_, c_, 0, 0, 0)

// chunked bijective XCD swizzle (requires nwg % 8 == 0; all our grids qualify)
__device__ __forceinline__ int xcd_logical() {
  int gx = gridDim.x, gy = gridDim.y, gz = gridDim.z;
  int pid = blockIdx.x + gx * (blockIdx.y + gy * blockIdx.z);
  int q = (gx * gy * gz) >> 3;
  return (pid & 7) * q + (pid >> 3);
}

// ---------------- mask scan: per batch, compaction tables ----------------
__global__ __launch_bounds__(256) void k_scan(const int* __restrict__ mask,
    int* __restrict__ idx, int* __restrict__ pfx, int* __restrict__ cnt,
    int* __restrict__ kpad) {
  __shared__ int cs[256];
  int b = blockIdx.x, t = threadIdx.x;
  const int* mrow = mask + (size_t)b * SS;
  int4 a = ((const int4*)mrow)[t * 2];
  int4 c2 = ((const int4*)mrow)[t * 2 + 1];
  int mm[8] = {a.x, a.y, a.z, a.w, c2.x, c2.y, c2.z, c2.w};
  int c = 0;
#pragma unroll
  for (int j = 0; j < 8; ++j) c += (mm[j] == 0);
  cs[t] = c;
  __syncthreads();
  if (t == 0) {
    int run = 0;
    for (int i = 0; i < 256; ++i) { int tmp = cs[i]; cs[i] = run; run += tmp; }
    cnt[b] = run;
    int kp = (run + 127) & ~127;
    if (kp > NMAX) kp = NMAX;
    kpad[b] = kp;
  }
  __syncthreads();
  int base = cs[t];
#pragma unroll
  for (int j = 0; j < 8; ++j) {
    int s = t * 8 + j;
    pfx[(size_t)b * SS + s] = base;
    if (mm[j] == 0) { idx[(size_t)b * SS + base] = s; base++; }
  }
}

// ---------------- split f32 -> bf16 hi/lo ----------------
__global__ __launch_bounds__(256) void k_split(const float* __restrict__ in,
    unsigned short* __restrict__ hi, unsigned short* __restrict__ lo, long n4) {
  long i = (long)blockIdx.x * blockDim.x + threadIdx.x;
  long stride = (long)gridDim.x * blockDim.x;
  for (; i < n4; i += stride) {
    float4 v = ((const float4*)in)[i];
    float f[4] = {v.x, v.y, v.z, v.w};
    unsigned short hh[4], ll[4];
#pragma unroll
    for (int j = 0; j < 4; ++j) {
      hh[j] = f2bf(f[j]);
      ll[j] = f2bf(f[j] - bf2f(hh[j]));
    }
    ushort4 h; h.x = hh[0]; h.y = hh[1]; h.z = hh[2]; h.w = hh[3];
    ushort4 l; l.x = ll[0]; l.y = ll[1]; l.z = ll[2]; l.w = ll[3];
    ((ushort4*)hi)[i] = h;
    ((ushort4*)lo)[i] = l;
  }
}

// ---------------- f32 -> bf16 convert ----------------
__global__ __launch_bounds__(256) void k_conv(const float* __restrict__ in,
    unsigned short* __restrict__ out, long n4) {
  long i = (long)blockIdx.x * blockDim.x + threadIdx.x;
  long stride = (long)gridDim.x * blockDim.x;
  for (; i < n4; i += stride) {
    float4 v = ((const float4*)in)[i];
    ushort4 h; h.x = f2bf(v.x); h.y = f2bf(v.y); h.z = f2bf(v.z); h.w = f2bf(v.w);
    ((ushort4*)out)[i] = h;
  }
}

// ------- enc_a compact transpose: a_tc[b][sc][e] = enc_a[b][e][idx[sc]], split hi/lo -------
__global__ __launch_bounds__(256) void k_ta(const float* __restrict__ enca,
    const int* __restrict__ idx, const int* __restrict__ cnt,
    unsigned short* __restrict__ hi, unsigned short* __restrict__ lo) {
  __shared__ float tile[64][65];
  int b = blockIdx.z, sc0 = blockIdx.x * 64, e0 = blockIdx.y * 64;
  int cb = cnt[b];
  const float* src = enca + (size_t)b * EE * SS;
  int t = threadIdx.x, tr = t >> 4, tc = (t & 15) * 4;
  int idxv[4];
#pragma unroll
  for (int j = 0; j < 4; ++j) {
    int sc = sc0 + tc + j;
    idxv[j] = (sc < cb) ? idx[(size_t)b * SS + sc] : -1;
  }
#pragma unroll
  for (int i = 0; i < 4; ++i) {
    int e = tr + i * 16;
#pragma unroll
    for (int j = 0; j < 4; ++j)
      tile[e][tc + j] = (idxv[j] >= 0) ? src[(size_t)(e0 + e) * SS + idxv[j]] : 0.f;
  }
  __syncthreads();
  size_t ob = (size_t)b * NMAX * EE;
#pragma unroll
  for (int i = 0; i < 4; ++i) {
    int c = tr + i * 16;   // sc-local
    unsigned short hh[4], ll[4];
#pragma unroll
    for (int j = 0; j < 4; ++j) {
      float f = tile[tc + j][c];
      hh[j] = f2bf(f);
      ll[j] = f2bf(f - bf2f(hh[j]));
    }
    ushort4 h; h.x = hh[0]; h.y = hh[1]; h.z = hh[2]; h.w = hh[3];
    ushort4 l; l.x = ll[0]; l.y = ll[1]; l.z = ll[2]; l.w = ll[3];
    *(ushort4*)(hi + ob + (size_t)(sc0 + c) * EE + e0 + tc) = h;
    *(ushort4*)(lo + ob + (size_t)(sc0 + c) * EE + e0 + tc) = l;
  }
}

// ------- enc_b compact transpose: b_tc[b][e][sc] = enc_b[b][idx[sc]][e], bf16 -------
__global__ __launch_bounds__(256) void k_tb(const float* __restrict__ encb,
    const int* __restrict__ idx, const int* __restrict__ cnt,
    unsigned short* __restrict__ out) {
  __shared__ float tile[64][65];
  int b = blockIdx.z, sc0 = blockIdx.x * 64, e0 = blockIdx.y * 64;
  int cb = cnt[b];
  const float* src = encb + (size_t)b * SS * EE;
  int t = threadIdx.x, tr = t >> 4, tc = (t & 15) * 4;
#pragma unroll
  for (int i = 0; i < 4; ++i) {
    int r = tr + i * 16;   // sc-local
    int sc = sc0 + r;
    int sidx = (sc < cb) ? idx[(size_t)b * SS + sc] : -1;
    float4 v;
    if (sidx >= 0) v = *(const float4*)(src + (size_t)sidx * EE + e0 + tc);
    else { v.x = v.y = v.z = v.w = 0.f; }
    tile[r][tc] = v.x; tile[r][tc + 1] = v.y; tile[r][tc + 2] = v.z; tile[r][tc + 3] = v.w;
  }
  __syncthreads();
  size_t ob = (size_t)b * EE * NMAX;
#pragma unroll
  for (int i = 0; i < 4; ++i) {
    int c = tr + i * 16;   // e-local
    unsigned short hh[4];
#pragma unroll
    for (int j = 0; j < 4; ++j) hh[j] = f2bf(tile[tc + j][c]);
    ushort4 h; h.x = hh[0]; h.y = hh[1]; h.z = hh[2]; h.w = hh[3];
    *(ushort4*)(out + ob + (size_t)(e0 + c) * NMAX + sc0 + tc) = h;
  }
}

// ================= plain bf16 GEMM, 256x256 tile, BK=64, 4 phases, dynamic K ==============
template <int EPI>
__global__ __launch_bounds__(512, 2) void k_gemm8(
    const unsigned short* __restrict__ A, const unsigned short* __restrict__ B,
    int N, int KROW, const int* __restrict__ kdyn, long sA, long sB, long sC,
    const float* __restrict__ bias, const float* __restrict__ addend,
    float* __restrict__ outF, unsigned short* __restrict__ outH, float scale) {
  extern __shared__ char lds[];
  const int tid = threadIdx.x, wave = tid >> 6, lane = tid & 63;
  int L = xcd_logical();
  const int n0 = (L % gridDim.x) * 256;
  int tmpL = L / gridDim.x;
  const int m0 = (tmpL % gridDim.y) * 256;
  const int b = tmpL / gridDim.y;
  const int KD = kdyn ? kdyn[b] : KROW;
  const int wm = wave >> 2, wn = wave & 3;
  const unsigned short* gA = A + (size_t)b * sA + (size_t)m0 * KROW;
  const unsigned short* gB = B + (size_t)b * sB + (size_t)n0 * KROW;
  const unsigned ldsB = ldsoff(lds);

  int srow[2], sk8[2];
#pragma unroll
  for (int s = 0; s < 2; ++s) {
    int l = swzi((s * 512 + tid) * 16);
    srow[s] = l >> 6;
    sk8[s] = (l >> 4) & 3;
  }
  const int aR = wm * 128 + (lane & 15);
  const int bR = wn * 64 + (lane & 15);
  const int kB = (lane >> 4) * 16;
  const int nkt = KD >> 6;

  f32x4 acc[8][4] = {};

  auto STG = [&](int t, int tensor, int ks) {
    const unsigned short* g = tensor ? gB : gA;
    char* dst = lds + (t & 1) * 65536 + tensor * 32768 + ks * 16384 + wave * 1024;
    size_t gk = (size_t)t * 64 + ks * 32;
#pragma unroll
    for (int s = 0; s < 2; ++s)
      gload16(g + ((size_t)srow[s] * KROW + gk + sk8[s] * 8), dst + s * 8192);
  };
  auto RA = [&](int t, int ks, int mf) {
    int lin = (aR + mf * 16) * 64 + kB;
    return ds128(ldsB + (t & 1) * 65536 + ks * 16384 + swzi(lin));
  };
  auto RB = [&](int t, int ks, int nf) {
    int lin = (bR + nf * 16) * 64 + kB;
    return ds128(ldsB + (t & 1) * 65536 + 32768 + ks * 16384 + swzi(lin));
  };

  STG(0, 1, 0); STG(0, 0, 0); STG(0, 0, 1); STG(0, 1, 1);
  if (nkt > 1) { STG(1, 1, 0); STG(1, 0, 0); }

  for (int u = 0; u < nkt; ++u) {
    if (u + 1 < nkt) { WAITV(8); } else { WAITV(0); }
    BAR();
    short8 bf[4], af[4];
#pragma unroll
    for (int nf = 0; nf < 4; ++nf) bf[nf] = RB(u, 0, nf);
#pragma unroll
    for (int mf = 0; mf < 4; ++mf) af[mf] = RA(u, 0, mf);
    if (u + 1 < nkt) { STG(u + 1, 0, 1); STG(u + 1, 1, 1); }
    BAR(); WAITL(0); SCH0(); PRIO1();
#pragma unroll
    for (int mf = 0; mf < 4; ++mf)
#pragma unroll
      for (int nf = 0; nf < 4; ++nf) acc[mf][nf] = MF(af[mf], bf[nf], acc[mf][nf]);
    PRIO0(); SCH0(); BAR();
#pragma unroll
    for (int mf = 0; mf < 4; ++mf) af[mf] = RA(u, 0, mf + 4);
    if (u + 2 < nkt) STG(u + 2, 1, 0);
    BAR(); WAITL(0); SCH0(); PRIO1();
#pragma unroll
    for (int mf = 0; mf < 4; ++mf)
#pragma unroll
      for (int nf = 0; nf < 4; ++nf) acc[mf + 4][nf] = MF(af[mf], bf[nf], acc[mf + 4][nf]);
    PRIO0(); SCH0();
    if (u + 2 < nkt) { WAITV(10); } else if (u + 1 < nkt) { WAITV(8); } else { WAITV(0); }
    BAR();
#pragma unroll
    for (int nf = 0; nf < 4; ++nf) bf[nf] = RB(u, 1, nf);
#pragma unroll
    for (int mf = 0; mf < 4; ++mf) af[mf] = RA(u, 1, mf);
    if (u + 2 < nkt) STG(u + 2, 0, 0);
    BAR(); WAITL(0); SCH0(); PRIO1();
#pragma unroll
    for (int mf = 0; mf < 4; ++mf)
#pragma unroll
      for (int nf = 0; nf < 4; ++nf) acc[mf][nf] = MF(af[mf], bf[nf], acc[mf][nf]);
    PRIO0(); SCH0(); BAR();
#pragma unroll
    for (int mf = 0; mf < 4; ++mf) af[mf] = RA(u, 1, mf + 4);
    BAR(); WAITL(0); SCH0(); PRIO1();
#pragma unroll
    for (int mf = 0; mf < 4; ++mf)
#pragma unroll
      for (int nf = 0; nf < 4; ++nf) acc[mf + 4][nf] = MF(af[mf], bf[nf], acc[mf + 4][nf]);
    PRIO0(); SCH0(); BAR();
  }

  const size_t cb = (size_t)b * sC;
  const int mB = m0 + wm * 128 + ((lane >> 4) << 2);
  const int nB = n0 + wn * 64 + (lane & 15);
#pragma unroll
  for (int mf = 0; mf < 8; ++mf)
#pragma unroll
    for (int j = 0; j < 4; ++j) {
      int m = mB + mf * 16 + j;
#pragma unroll
      for (int nf = 0; nf < 4; ++nf) {
        int n = nB + nf * 16;
        float v = acc[mf][nf][j];
        size_t o = (size_t)m * N + n;
        if (EPI == 2) outH[cb + o] = f2bf(v * scale);
        else outF[o] = (v + bias[n] + addend[o]) * scale;
      }
    }
}

// ====== split (hi/lo) GEMM, 128x128 tile, 256 threads, BK=32, 3 phases, 1-buffer 32KB ======
// Residency-optimized core: ~3 blocks/CU (4-wave blocks, 32KB LDS, <=170 regs).
// Regions: Ah@0 (8K), Al@8K, Bh@16K, Bl@24K. 2 stage units each.
// Stage: ph1 -> Al[u]; ph2 -> Bh[u+1], Ah[u+1]; ph3 -> Bl[u+1].
// vmcnt (2-unit regions): steady (2)/(2)/(4); last tile (2)/(2)/(0). Prologue Bh,Ah,Bl.
// EPI: 0 = h epilogue (bias+addend,*scale, split bf16 out), 1 = raw f32 out (scores)
template <int EPI>
__global__ __launch_bounds__(256, 3) void k_split128(
    const unsigned short* __restrict__ Ah, const unsigned short* __restrict__ Al,
    const unsigned short* __restrict__ Bh, const unsigned short* __restrict__ Bl,
    int N, int K, long sA, long sB, long sC,
    const float* __restrict__ bias, const float* __restrict__ addend,
    float* __restrict__ outF, unsigned short* __restrict__ outHi,
    unsigned short* __restrict__ outLo, float scale, const int* __restrict__ npad) {
  extern __shared__ char lds[];
  const int tid = threadIdx.x, wave = tid >> 6, lane = tid & 63;
  int L = xcd_logical();
  const int n0 = (L % gridDim.x) * 128;
  int tmpL = L / gridDim.x;
  const int m0 = (tmpL % gridDim.y) * 128;
  const int b = tmpL / gridDim.y;
  if (npad && n0 >= npad[b]) return;
  const int wm = wave >> 1, wn = wave & 1;   // 2x2 waves; wave owns 64x64
  const unsigned short* gb[4];
  gb[0] = Ah + (size_t)b * sA + (size_t)m0 * K;
  gb[1] = Al + (size_t)b * sA + (size_t)m0 * K;
  gb[2] = Bh + (size_t)b * sB + (size_t)n0 * K;
  gb[3] = Bl + (size_t)b * sB + (size_t)n0 * K;
  const unsigned ldsB = ldsoff(lds);

  int soff[2];
#pragma unroll
  for (int s = 0; s < 2; ++s) {
    int l = swzi(s * 4096 + tid * 16);
    soff[s] = (l >> 6) * K + ((l >> 4) & 3) * 8;
  }
  const int aR = wm * 64 + (lane & 15);
  const int bR = wn * 64 + (lane & 15);
  const int kB = (lane >> 4) * 16;
  const int nkt = K >> 5;

  const unsigned vA = ldsB + (unsigned)swzi(aR * 64 + kB);          // Ah; Al = +8192
  const unsigned vB = ldsB + 16384u + (unsigned)swzi(bR * 64 + kB); // Bh; Bl = +8192

  f32x4 acc[4][4] = {};

  auto STG = [&](int t, int r) {   // region r, 2 units
    char* dst = lds + r * 8192 + tid * 16;
    const unsigned short* g = gb[r] + (size_t)t * 32;
    gload16(g + soff[0], dst);
    gload16(g + soff[1], dst + 4096);
  };

#define TILE3(u, WV1, WV2, WV3, STAGE) do {                                    \
  short8 ahi[4], bhi[4], blo[4], alo[4];                                       \
  /* ph1: hi*hi */                                                             \
  WV1; BAR();                                                                  \
  _Pragma("unroll") for (int q = 0; q < 4; ++q) bhi[q] = ds128(vB + q * 1024); \
  _Pragma("unroll") for (int q = 0; q < 4; ++q) ahi[q] = ds128(vA + q * 1024); \
  STG(u, 1);                                                                   \
  BAR(); WAITL(0); SCH0(); PRIO1();                                            \
  _Pragma("unroll") for (int mi = 0; mi < 4; ++mi)                             \
  _Pragma("unroll") for (int ni = 0; ni < 4; ++ni)                             \
    acc[mi][ni] = MF(ahi[mi], bhi[ni], acc[mi][ni]);                           \
  PRIO0(); SCH0();                                                             \
  /* ph2: hi*lo */                                                             \
  WV2; BAR();                                                                  \
  _Pragma("unroll") for (int q = 0; q < 4; ++q) blo[q] = ds128(vB + 8192 + q * 1024); \
  if (STAGE) { STG((u) + 1, 2); STG((u) + 1, 0); }                             \
  BAR(); WAITL(0); SCH0(); PRIO1();                                            \
  _Pragma("unroll") for (int mi = 0; mi < 4; ++mi)                             \
  _Pragma("unroll") for (int ni = 0; ni < 4; ++ni)                             \
    acc[mi][ni] = MF(ahi[mi], blo[ni], acc[mi][ni]);                           \
  PRIO0(); SCH0();                                                             \
  /* ph3: lo*hi */                                                             \
  WV3; BAR();                                                                  \
  _Pragma("unroll") for (int q = 0; q < 4; ++q) alo[q] = ds128(vA + 8192 + q * 1024); \
  if (STAGE) STG((u) + 1, 3);                                                  \
  BAR(); WAITL(0); SCH0(); PRIO1();                                            \
  _Pragma("unroll") for (int mi = 0; mi < 4; ++mi)                             \
  _Pragma("unroll") for (int ni = 0; ni < 4; ++ni)                             \
    acc[mi][ni] = MF(alo[mi], bhi[ni], acc[mi][ni]);                           \
  PRIO0(); SCH0();                                                             \
} while (0)

  // prologue: Bh[0], Ah[0], Bl[0] (2 units each -> 6 outstanding)
  STG(0, 2); STG(0, 0); STG(0, 3);

  for (int u = 0; u < nkt - 1; ++u)
    TILE3(u, WAITV(2), WAITV(2), WAITV(4), 1);
  TILE3(nkt - 1, WAITV(2), WAITV(2), WAITV(0), 0);
#undef TILE3

  const size_t cb = (size_t)b * sC;
  const int mB = m0 + wm * 64 + ((lane >> 4) << 2);
  const int nB = n0 + wn * 64 + (lane & 15);
#pragma unroll
  for (int mf = 0; mf < 4; ++mf)
#pragma unroll
    for (int j = 0; j < 4; ++j) {
      int m = mB + mf * 16 + j;
#pragma unroll
      for (int nf = 0; nf < 4; ++nf) {
        int n = nB + nf * 16;
        float v = acc[mf][nf][j];
        size_t o = (size_t)m * N + n;
        if (EPI == 0) {
          v = (v + bias[n] + addend[o]) * scale;
          unsigned short hb = f2bf(v);
          outHi[o] = hb;
          outLo[o] = f2bf(v - bf2f(hb));
        } else {
          outF[cb + o] = v;
        }
      }
    }
}

// -------- softmax: compact scores row -> full f32 attn row + compact bf16 attn --------
__global__ __launch_bounds__(256) void k_softmax(const float* __restrict__ scores_c,
    float* __restrict__ attn, unsigned short* __restrict__ attn_bc,
    const int* __restrict__ mask, const int* __restrict__ pfx,
    const int* __restrict__ cnt, const int* __restrict__ kpad) {
  __shared__ float sl[NMAX];
  __shared__ float red[8];
  long r = blockIdx.x;
  int b = (int)(r >> 11);
  int t = threadIdx.x;
  int cb = cnt[b], kp = kpad[b];
  const float* srow = scores_c + r * (long)NMAX;
  for (int i = t; i < cb; i += 256) sl[i] = srow[i];
  __syncthreads();
  int base = t * 8;
  const int* mrow = mask + (size_t)b * SS;
  int4 m0i = *(const int4*)(mrow + base);
  int4 m1i = *(const int4*)(mrow + base + 4);
  int mm[8] = {m0i.x, m0i.y, m0i.z, m0i.w, m1i.x, m1i.y, m1i.z, m1i.w};
  const int* prow = pfx + (size_t)b * SS;
  int4 p0i = *(const int4*)(prow + base);
  int4 p1i = *(const int4*)(prow + base + 4);
  int pp[8] = {p0i.x, p0i.y, p0i.z, p0i.w, p1i.x, p1i.y, p1i.z, p1i.w};
  float v[8];
#pragma unroll
  for (int j = 0; j < 8; ++j) v[j] = mm[j] ? -INFINITY : sl[pp[j]];
  float mx = v[0];
#pragma unroll
  for (int j = 1; j < 8; ++j) mx = fmaxf(mx, v[j]);
#pragma unroll
  for (int off = 32; off; off >>= 1) mx = fmaxf(mx, __shfl_xor(mx, off));
  int wv = t >> 6, ln = t & 63;
  if (ln == 0) red[wv] = mx;
  __syncthreads();
  mx = fmaxf(fmaxf(red[0], red[1]), fmaxf(red[2], red[3]));
  float sum = 0.f;
#pragma unroll
  for (int j = 0; j < 8; ++j) { v[j] = __expf(v[j] - mx); sum += v[j]; }
#pragma unroll
  for (int off = 32; off; off >>= 1) sum += __shfl_xor(sum, off);
  if (ln == 0) red[4 + wv] = sum;
  __syncthreads();
  sum = (red[4] + red[5]) + (red[6] + red[7]);
  float inv = 1.0f / sum;
#pragma unroll
  for (int j = 0; j < 8; ++j) v[j] *= inv;
  float* arow = attn + r * (long)SS;
  float4 w0; w0.x = v[0]; w0.y = v[1]; w0.z = v[2]; w0.w = v[3];
  float4 w1; w1.x = v[4]; w1.y = v[5]; w1.z = v[6]; w1.w = v[7];
  *(float4*)(arow + base) = w0;
  *(float4*)(arow + base + 4) = w1;
  __syncthreads();          // sl reads done; reuse for compact attn
#pragma unroll
  for (int j = 0; j < 8; ++j) if (!mm[j]) sl[pp[j]] = v[j];
  __syncthreads();
  unsigned short* brow = attn_bc + r * (long)NMAX;
  for (int i = t; i < kp; i += 256) brow[i] = f2bf(i < cb ? sl[i] : 0.f);
}

extern "C" void kernel_launch(void* const* d_in, const int* in_sizes, int n_in,
                              void* d_out, int out_size, void* d_ws, size_t ws_size,
                              hipStream_t stream) {
  (void)in_sizes; (void)n_in; (void)out_size; (void)ws_size;
  const float* x     = (const float*)d_in[0];
  const float* tgt   = (const float*)d_in[1];
  const float* enca  = (const float*)d_in[2];
  const float* encb  = (const float*)d_in[3];
  const int*   mask  = (const int*)d_in[4];
  const float* w_in  = (const float*)d_in[5];
  const float* b_in  = (const float*)d_in[6];
  const float* w_out = (const float*)d_in[7];
  const float* b_out = (const float*)d_in[8];

  float* out  = (float*)d_out;                       // [B,T,C]
  float* attn = out + (size_t)NB * TT * CC;          // [B,T,S]

  char* ws = (char*)d_ws;
  // liveness-phased layout (NMAX=1280)
  float*          scores_c = (float*)(ws + 0);                    // [0, 83886080)
  unsigned short* x_hi   = (unsigned short*)(ws + 0);             // dead before scores
  unsigned short* x_lo   = (unsigned short*)(ws + 33554432L);
  unsigned short* pv     = (unsigned short*)(ws + 0);             // after softmax
  unsigned short* h_hi   = (unsigned short*)(ws + 83886080L);
  unsigned short* h_lo   = (unsigned short*)(ws + 117440512L);
  unsigned short* attn_bc= (unsigned short*)(ws + 83886080L);     // after scores (h dead)
  unsigned short* a_tc_hi= (unsigned short*)(ws + 150994944L);
  unsigned short* a_tc_lo= (unsigned short*)(ws + 171966464L);
  unsigned short* b_tc   = (unsigned short*)(ws + 192937984L);
  unsigned short* w_in_hi= (unsigned short*)(ws + 213909504L);
  unsigned short* w_in_lo= (unsigned short*)(ws + 216006656L);
  unsigned short* w_out_b= (unsigned short*)(ws + 218103808L);
  int* idx  = (int*)(ws + 220200960L);
  int* pfx  = (int*)(ws + 220266496L);
  int* cnt  = (int*)(ws + 220332032L);
  int* kpad = (int*)(ws + 220332096L);

  hipFuncSetAttribute(reinterpret_cast<const void*>(&k_gemm8<2>),
                      hipFuncAttributeMaxDynamicSharedMemorySize, 131072);
  hipFuncSetAttribute(reinterpret_cast<const void*>(&k_gemm8<3>),
                      hipFuncAttributeMaxDynamicSharedMemorySize, 131072);
  hipFuncSetAttribute(reinterpret_cast<const void*>(&k_split128<0>),
                      hipFuncAttributeMaxDynamicSharedMemorySize, 32768);
  hipFuncSetAttribute(reinterpret_cast<const void*>(&k_split128<1>),
                      hipFuncAttributeMaxDynamicSharedMemorySize, 32768);

  dim3 blk(256), blk512(512);
  const float S05 = 0.70710678118654752f;

  k_scan<<<NB, blk, 0, stream>>>(mask, idx, pfx, cnt, kpad);
  k_split<<<2048, blk, 0, stream>>>(x, x_hi, x_lo, (long)NB * TT * CC / 4);
  k_split<<<512, blk, 0, stream>>>(w_in, w_in_hi, w_in_lo, (long)EE * CC / 4);
  k_conv<<<512, blk, 0, stream>>>(w_out, w_out_b, (long)CC * EE / 4);
  k_ta<<<dim3(NMAX / 64, EE / 64, NB), blk, 0, stream>>>(enca, idx, cnt, a_tc_hi, a_tc_lo);
  k_tb<<<dim3(NMAX / 64, EE / 64, NB), blk, 0, stream>>>(encb, idx, cnt, b_tc);

  // GEMM1: h = (x @ w_in^T + b_in + tgt) * sqrt(0.5). 128^2 3-block/CU core, 1024 blocks.
  k_split128<0><<<dim3(EE / 128, (NB * TT) / 128, 1), blk, 32768, stream>>>(
      x_hi, x_lo, w_in_hi, w_in_lo, EE, CC, 0, 0, 0,
      b_in, tgt, nullptr, h_hi, h_lo, S05, nullptr);

  // scores_c = h @ a_tc (compact, batched). 128x128 3-block/CU core, 1280 blocks.
  k_split128<1><<<dim3(NMAX / 128, TT / 128, NB), blk, 32768, stream>>>(
      h_hi, h_lo, a_tc_hi, a_tc_lo, NMAX, EE,
      (long)TT * EE, (long)NMAX * EE, (long)TT * NMAX,
      nullptr, nullptr, scores_c, nullptr, nullptr, 1.0f, kpad);

  // masked softmax on compact domain; writes full attn (f32) + compact attn_bc (bf16)
  k_softmax<<<NB * TT, blk, 0, stream>>>(scores_c, attn, attn_bc, mask, pfx, cnt, kpad);

  // pv = (attn_bc @ b_tc) * sqrt(S), dynamic K = kpad[b], bf16 out
  k_gemm8<2><<<dim3(EE / 256, TT / 256, NB), blk512, 131072, stream>>>(
      attn_bc, b_tc, EE, NMAX, kpad,
      (long)TT * NMAX, (long)EE * NMAX, (long)TT * EE,
      nullptr, nullptr, nullptr, pv, 45.254833995939045f);

  // out = (pv @ w_out^T + b_out + x) * sqrt(0.5)
  k_gemm8<3><<<dim3(CC / 256, (NB * TT) / 256, 1), blk512, 131072, stream>>>(
      pv, w_out_b, CC, EE, nullptr, 0, 0, 0,
      b_out, x, out, nullptr, S05);
}

// Round 15
// 480.048 us; speedup vs baseline: 1.0325x; 1.0325x over previous
//
#include <hip/hip_runtime.h>
#include <hip/hip_bf16.h>
#include <math.h>

#define NB 8
#define TT 2048
#define SS 2048
#define CC 1024
#define EE 1024
#define NMAX 1280

typedef __attribute__((ext_vector_type(8))) short short8;
typedef __attribute__((ext_vector_type(4))) float f32x4;

__device__ __forceinline__ unsigned short f2bf(float f) {
  unsigned u = __builtin_bit_cast(unsigned, f);
  u += 0x7fffu + ((u >> 16) & 1u);          // RNE
  return (unsigned short)(u >> 16);
}
__device__ __forceinline__ float bf2f(unsigned short h) {
  unsigned u = ((unsigned)h) << 16;
  return __builtin_bit_cast(float, u);
}
__device__ __forceinline__ void gload16(const void* g, void* l) {
  __builtin_amdgcn_global_load_lds((const __attribute__((address_space(1))) void*)g,
                                   (__attribute__((address_space(3))) void*)l, 16, 0, 0);
}
__device__ __forceinline__ unsigned ldsoff(const void* p) {
  return (unsigned)(size_t)(const __attribute__((address_space(3))) char*)p;
}
__device__ __forceinline__ short8 ds128(unsigned off) {
  short8 r;
  asm volatile("ds_read_b128 %0, %1" : "=v"(r) : "v"(off));
  return r;
}
// XOR swizzle: bits 4-6 ^= bits 7-9 (involution)
__device__ __forceinline__ int swzi(int x) { return x ^ (((x >> 7) & 7) << 4); }

#define WAITV(N) asm volatile("s_waitcnt vmcnt(" #N ")" ::: "memory")
#define WAITL(N) asm volatile("s_waitcnt lgkmcnt(" #N ")" ::: "memory")
#define BAR() __builtin_amdgcn_s_barrier()
#define SCH0() __builtin_amdgcn_sched_barrier(0)
#define PRIO1() __builtin_amdgcn_s_setprio(1)
#define PRIO0() __builtin_amdgcn_s_setprio(0)
#define MF(a_, b_, c_) __builtin_amdgcn_mfma_f32_16x16x32_bf16(a_, b_, c_, 0, 0, 0)

// chunked bijective XCD swizzle (requires nwg % 8 == 0; all our grids qualify)
__device__ __forceinline__ int xcd_logical() {
  int gx = gridDim.x, gy = gridDim.y, gz = gridDim.z;
  int pid = blockIdx.x + gx * (blockIdx.y + gy * blockIdx.z);
  int q = (gx * gy * gz) >> 3;
  return (pid & 7) * q + (pid >> 3);
}

// ---------------- mask scan: per batch, compaction tables ----------------
__global__ __launch_bounds__(256) void k_scan(const int* __restrict__ mask,
    int* __restrict__ idx, int* __restrict__ pfx, int* __restrict__ cnt,
    int* __restrict__ kpad) {
  __shared__ int cs[256];
  int b = blockIdx.x, t = threadIdx.x;
  const int* mrow = mask + (size_t)b * SS;
  int4 a = ((const int4*)mrow)[t * 2];
  int4 c2 = ((const int4*)mrow)[t * 2 + 1];
  int mm[8] = {a.x, a.y, a.z, a.w, c2.x, c2.y, c2.z, c2.w};
  int c = 0;
#pragma unroll
  for (int j = 0; j < 8; ++j) c += (mm[j] == 0);
  cs[t] = c;
  __syncthreads();
  if (t == 0) {
    int run = 0;
    for (int i = 0; i < 256; ++i) { int tmp = cs[i]; cs[i] = run; run += tmp; }
    cnt[b] = run;
    int kp = (run + 127) & ~127;
    if (kp > NMAX) kp = NMAX;
    kpad[b] = kp;
  }
  __syncthreads();
  int base = cs[t];
#pragma unroll
  for (int j = 0; j < 8; ++j) {
    int s = t * 8 + j;
    pfx[(size_t)b * SS + s] = base;
    if (mm[j] == 0) { idx[(size_t)b * SS + base] = s; base++; }
  }
}

// ---------------- split f32 -> bf16 hi/lo ----------------
__global__ __launch_bounds__(256) void k_split(const float* __restrict__ in,
    unsigned short* __restrict__ hi, unsigned short* __restrict__ lo, long n4) {
  long i = (long)blockIdx.x * blockDim.x + threadIdx.x;
  long stride = (long)gridDim.x * blockDim.x;
  for (; i < n4; i += stride) {
    float4 v = ((const float4*)in)[i];
    float f[4] = {v.x, v.y, v.z, v.w};
    unsigned short hh[4], ll[4];
#pragma unroll
    for (int j = 0; j < 4; ++j) {
      hh[j] = f2bf(f[j]);
      ll[j] = f2bf(f[j] - bf2f(hh[j]));
    }
    ushort4 h; h.x = hh[0]; h.y = hh[1]; h.z = hh[2]; h.w = hh[3];
    ushort4 l; l.x = ll[0]; l.y = ll[1]; l.z = ll[2]; l.w = ll[3];
    ((ushort4*)hi)[i] = h;
    ((ushort4*)lo)[i] = l;
  }
}

// ---------------- f32 -> bf16 convert ----------------
__global__ __launch_bounds__(256) void k_conv(const float* __restrict__ in,
    unsigned short* __restrict__ out, long n4) {
  long i = (long)blockIdx.x * blockDim.x + threadIdx.x;
  long stride = (long)gridDim.x * blockDim.x;
  for (; i < n4; i += stride) {
    float4 v = ((const float4*)in)[i];
    ushort4 h; h.x = f2bf(v.x); h.y = f2bf(v.y); h.z = f2bf(v.z); h.w = f2bf(v.w);
    ((ushort4*)out)[i] = h;
  }
}

// ------- enc_a compact transpose: a_tc[b][sc][e] = enc_a[b][e][idx[sc]], split hi/lo -------
__global__ __launch_bounds__(256) void k_ta(const float* __restrict__ enca,
    const int* __restrict__ idx, const int* __restrict__ cnt,
    unsigned short* __restrict__ hi, unsigned short* __restrict__ lo) {
  __shared__ float tile[64][65];
  int b = blockIdx.z, sc0 = blockIdx.x * 64, e0 = blockIdx.y * 64;
  int cb = cnt[b];
  const float* src = enca + (size_t)b * EE * SS;
  int t = threadIdx.x, tr = t >> 4, tc = (t & 15) * 4;
  int idxv[4];
#pragma unroll
  for (int j = 0; j < 4; ++j) {
    int sc = sc0 + tc + j;
    idxv[j] = (sc < cb) ? idx[(size_t)b * SS + sc] : -1;
  }
#pragma unroll
  for (int i = 0; i < 4; ++i) {
    int e = tr + i * 16;
#pragma unroll
    for (int j = 0; j < 4; ++j)
      tile[e][tc + j] = (idxv[j] >= 0) ? src[(size_t)(e0 + e) * SS + idxv[j]] : 0.f;
  }
  __syncthreads();
  size_t ob = (size_t)b * NMAX * EE;
#pragma unroll
  for (int i = 0; i < 4; ++i) {
    int c = tr + i * 16;   // sc-local
    unsigned short hh[4], ll[4];
#pragma unroll
    for (int j = 0; j < 4; ++j) {
      float f = tile[tc + j][c];
      hh[j] = f2bf(f);
      ll[j] = f2bf(f - bf2f(hh[j]));
    }
    ushort4 h; h.x = hh[0]; h.y = hh[1]; h.z = hh[2]; h.w = hh[3];
    ushort4 l; l.x = ll[0]; l.y = ll[1]; l.z = ll[2]; l.w = ll[3];
    *(ushort4*)(hi + ob + (size_t)(sc0 + c) * EE + e0 + tc) = h;
    *(ushort4*)(lo + ob + (size_t)(sc0 + c) * EE + e0 + tc) = l;
  }
}

// ------- enc_b compact transpose: b_tc[b][e][sc] = enc_b[b][idx[sc]][e], bf16 -------
__global__ __launch_bounds__(256) void k_tb(const float* __restrict__ encb,
    const int* __restrict__ idx, const int* __restrict__ cnt,
    unsigned short* __restrict__ out) {
  __shared__ float tile[64][65];
  int b = blockIdx.z, sc0 = blockIdx.x * 64, e0 = blockIdx.y * 64;
  int cb = cnt[b];
  const float* src = encb + (size_t)b * SS * EE;
  int t = threadIdx.x, tr = t >> 4, tc = (t & 15) * 4;
#pragma unroll
  for (int i = 0; i < 4; ++i) {
    int r = tr + i * 16;   // sc-local
    int sc = sc0 + r;
    int sidx = (sc < cb) ? idx[(size_t)b * SS + sc] : -1;
    float4 v;
    if (sidx >= 0) v = *(const float4*)(src + (size_t)sidx * EE + e0 + tc);
    else { v.x = v.y = v.z = v.w = 0.f; }
    tile[r][tc] = v.x; tile[r][tc + 1] = v.y; tile[r][tc + 2] = v.z; tile[r][tc + 3] = v.w;
  }
  __syncthreads();
  size_t ob = (size_t)b * EE * NMAX;
#pragma unroll
  for (int i = 0; i < 4; ++i) {
    int c = tr + i * 16;   // e-local
    unsigned short hh[4];
#pragma unroll
    for (int j = 0; j < 4; ++j) hh[j] = f2bf(tile[tc + j][c]);
    ushort4 h; h.x = hh[0]; h.y = hh[1]; h.z = hh[2]; h.w = hh[3];
    *(ushort4*)(out + ob + (size_t)(e0 + c) * NMAX + sc0 + tc) = h;
  }
}

// ================= plain bf16 GEMM, 256x256 tile, BK=64, 4 phases, dynamic K ==============
template <int EPI>
__global__ __launch_bounds__(512, 2) void k_gemm8(
    const unsigned short* __restrict__ A, const unsigned short* __restrict__ B,
    int N, int KROW, const int* __restrict__ kdyn, long sA, long sB, long sC,
    const float* __restrict__ bias, const float* __restrict__ addend,
    float* __restrict__ outF, unsigned short* __restrict__ outH, float scale) {
  extern __shared__ char lds[];
  const int tid = threadIdx.x, wave = tid >> 6, lane = tid & 63;
  int L = xcd_logical();
  const int n0 = (L % gridDim.x) * 256;
  int tmpL = L / gridDim.x;
  const int m0 = (tmpL % gridDim.y) * 256;
  const int b = tmpL / gridDim.y;
  const int KD = kdyn ? kdyn[b] : KROW;
  const int wm = wave >> 2, wn = wave & 3;
  const unsigned short* gA = A + (size_t)b * sA + (size_t)m0 * KROW;
  const unsigned short* gB = B + (size_t)b * sB + (size_t)n0 * KROW;
  const unsigned ldsB = ldsoff(lds);

  int srow[2], sk8[2];
#pragma unroll
  for (int s = 0; s < 2; ++s) {
    int l = swzi((s * 512 + tid) * 16);
    srow[s] = l >> 6;
    sk8[s] = (l >> 4) & 3;
  }
  const int aR = wm * 128 + (lane & 15);
  const int bR = wn * 64 + (lane & 15);
  const int kB = (lane >> 4) * 16;
  const int nkt = KD >> 6;

  f32x4 acc[8][4] = {};

  auto STG = [&](int t, int tensor, int ks) {
    const unsigned short* g = tensor ? gB : gA;
    char* dst = lds + (t & 1) * 65536 + tensor * 32768 + ks * 16384 + wave * 1024;
    size_t gk = (size_t)t * 64 + ks * 32;
#pragma unroll
    for (int s = 0; s < 2; ++s)
      gload16(g + ((size_t)srow[s] * KROW + gk + sk8[s] * 8), dst + s * 8192);
  };
  auto RA = [&](int t, int ks, int mf) {
    int lin = (aR + mf * 16) * 64 + kB;
    return ds128(ldsB + (t & 1) * 65536 + ks * 16384 + swzi(lin));
  };
  auto RB = [&](int t, int ks, int nf) {
    int lin = (bR + nf * 16) * 64 + kB;
    return ds128(ldsB + (t & 1) * 65536 + 32768 + ks * 16384 + swzi(lin));
  };

  STG(0, 1, 0); STG(0, 0, 0); STG(0, 0, 1); STG(0, 1, 1);
  if (nkt > 1) { STG(1, 1, 0); STG(1, 0, 0); }

  for (int u = 0; u < nkt; ++u) {
    if (u + 1 < nkt) { WAITV(8); } else { WAITV(0); }
    BAR();
    short8 bf[4], af[4];
#pragma unroll
    for (int nf = 0; nf < 4; ++nf) bf[nf] = RB(u, 0, nf);
#pragma unroll
    for (int mf = 0; mf < 4; ++mf) af[mf] = RA(u, 0, mf);
    if (u + 1 < nkt) { STG(u + 1, 0, 1); STG(u + 1, 1, 1); }
    BAR(); WAITL(0); SCH0(); PRIO1();
#pragma unroll
    for (int mf = 0; mf < 4; ++mf)
#pragma unroll
      for (int nf = 0; nf < 4; ++nf) acc[mf][nf] = MF(af[mf], bf[nf], acc[mf][nf]);
    PRIO0(); SCH0(); BAR();
#pragma unroll
    for (int mf = 0; mf < 4; ++mf) af[mf] = RA(u, 0, mf + 4);
    if (u + 2 < nkt) STG(u + 2, 1, 0);
    BAR(); WAITL(0); SCH0(); PRIO1();
#pragma unroll
    for (int mf = 0; mf < 4; ++mf)
#pragma unroll
      for (int nf = 0; nf < 4; ++nf) acc[mf + 4][nf] = MF(af[mf], bf[nf], acc[mf + 4][nf]);
    PRIO0(); SCH0();
    if (u + 2 < nkt) { WAITV(10); } else if (u + 1 < nkt) { WAITV(8); } else { WAITV(0); }
    BAR();
#pragma unroll
    for (int nf = 0; nf < 4; ++nf) bf[nf] = RB(u, 1, nf);
#pragma unroll
    for (int mf = 0; mf < 4; ++mf) af[mf] = RA(u, 1, mf);
    if (u + 2 < nkt) STG(u + 2, 0, 0);
    BAR(); WAITL(0); SCH0(); PRIO1();
#pragma unroll
    for (int mf = 0; mf < 4; ++mf)
#pragma unroll
      for (int nf = 0; nf < 4; ++nf) acc[mf][nf] = MF(af[mf], bf[nf], acc[mf][nf]);
    PRIO0(); SCH0(); BAR();
#pragma unroll
    for (int mf = 0; mf < 4; ++mf) af[mf] = RA(u, 1, mf + 4);
    BAR(); WAITL(0); SCH0(); PRIO1();
#pragma unroll
    for (int mf = 0; mf < 4; ++mf)
#pragma unroll
      for (int nf = 0; nf < 4; ++nf) acc[mf + 4][nf] = MF(af[mf], bf[nf], acc[mf + 4][nf]);
    PRIO0(); SCH0(); BAR();
  }

  const size_t cb = (size_t)b * sC;
  const int mB = m0 + wm * 128 + ((lane >> 4) << 2);
  const int nB = n0 + wn * 64 + (lane & 15);
#pragma unroll
  for (int mf = 0; mf < 8; ++mf)
#pragma unroll
    for (int j = 0; j < 4; ++j) {
      int m = mB + mf * 16 + j;
#pragma unroll
      for (int nf = 0; nf < 4; ++nf) {
        int n = nB + nf * 16;
        float v = acc[mf][nf][j];
        size_t o = (size_t)m * N + n;
        if (EPI == 2) outH[cb + o] = f2bf(v * scale);
        else outF[o] = (v + bias[n] + addend[o]) * scale;
      }
    }
}

// ============ split (hi/lo) GEMM, 256x256 tile, BK=32, 3 products, 6 sub-phases ============
// R5/R9-proven schedule (52% MfmaUtil), double-buffered 128KB. Used for GEMM1.
template <int EPI>
__global__ __launch_bounds__(512, 2) void k_split6(
    const unsigned short* __restrict__ Ah, const unsigned short* __restrict__ Al,
    const unsigned short* __restrict__ Bh, const unsigned short* __restrict__ Bl,
    int N, int K, long sA, long sB, long sC,
    const float* __restrict__ bias, const float* __restrict__ addend,
    float* __restrict__ outF, unsigned short* __restrict__ outHi,
    unsigned short* __restrict__ outLo, float scale, const int* __restrict__ npad) {
  extern __shared__ char lds[];
  const int tid = threadIdx.x, wave = tid >> 6, lane = tid & 63;
  int L = xcd_logical();
  const int n0 = (L % gridDim.x) * 256;
  int tmpL = L / gridDim.x;
  const int m0 = (tmpL % gridDim.y) * 256;
  const int b = tmpL / gridDim.y;
  if (npad && n0 >= npad[b]) return;
  const int wm = wave >> 2, wn = wave & 3;
  const unsigned short* gb[4];
  gb[0] = Ah + (size_t)b * sA + (size_t)m0 * K;
  gb[1] = Al + (size_t)b * sA + (size_t)m0 * K;
  gb[2] = Bh + (size_t)b * sB + (size_t)n0 * K;
  gb[3] = Bl + (size_t)b * sB + (size_t)n0 * K;
  const unsigned ldsB = ldsoff(lds);

  int soff[2];
#pragma unroll
  for (int s = 0; s < 2; ++s) {
    int l = swzi((s * 512 + tid) * 16);
    soff[s] = (l >> 6) * K + ((l >> 4) & 3) * 8;
  }
  const int aR = wm * 128 + (lane & 15);
  const int bR = wn * 64 + (lane & 15);
  const int kB = (lane >> 4) * 16;
  const int nkt = K >> 5;

  unsigned vA = ldsB + (unsigned)swzi(aR * 64 + kB);
  unsigned vB = ldsB + (unsigned)swzi(bR * 64 + kB);

  f32x4 acc[8][4] = {};

  auto STG2 = [&](int t, unsigned bufbase, int region) {
    char* dst = lds + bufbase + region * 16384 + tid * 16;
    const unsigned short* g = gb[region] + (size_t)t * 32;
#pragma unroll
    for (int s = 0; s < 2; ++s)
      gload16(g + soff[s], dst + s * 8192);
  };

#define PH_TOP() BAR()
#define PH_MID() BAR(); WAITL(0); SCH0(); PRIO1()
#define PH_END() PRIO0(); SCH0()

#define TILE(u, WV1, WV3, WV5, STAGE) do {                                     \
  short8 ahi[8], bhi[4], blo[4], alo[4];                                       \
  /* ph1: hi*hi mf0-3 */                                                       \
  WV1; PH_TOP();                                                               \
  _Pragma("unroll") for (int q = 0; q < 4; ++q) bhi[q] = ds128(vB + 32768 + q * 1024); \
  _Pragma("unroll") for (int q = 0; q < 4; ++q) ahi[q] = ds128(vA + q * 1024); \
  if (STAGE) STG2((u) + 1, nbuf, 0);                                           \
  PH_MID();                                                                    \
  _Pragma("unroll") for (int mi = 0; mi < 4; ++mi)                             \
  _Pragma("unroll") for (int ni = 0; ni < 4; ++ni)                             \
    acc[mi][ni] = MF(ahi[mi], bhi[ni], acc[mi][ni]);                           \
  PH_END();                                                                    \
  /* ph2: hi*hi mf4-7 */                                                       \
  PH_TOP();                                                                    \
  _Pragma("unroll") for (int q = 0; q < 4; ++q) ahi[4 + q] = ds128(vA + (4 + q) * 1024); \
  if (STAGE) STG2((u) + 1, nbuf, 2);                                           \
  PH_MID();                                                                    \
  _Pragma("unroll") for (int mi = 0; mi < 4; ++mi)                             \
  _Pragma("unroll") for (int ni = 0; ni < 4; ++ni)                             \
    acc[4 + mi][ni] = MF(ahi[4 + mi], bhi[ni], acc[4 + mi][ni]);               \
  PH_END();                                                                    \
  /* ph3: hi*lo mf0-3 */                                                       \
  WV3; PH_TOP();                                                               \
  _Pragma("unroll") for (int q = 0; q < 4; ++q) blo[q] = ds128(vB + 49152 + q * 1024); \
  if (STAGE) STG2((u) + 1, nbuf, 3);                                           \
  PH_MID();                                                                    \
  _Pragma("unroll") for (int mi = 0; mi < 4; ++mi)                             \
  _Pragma("unroll") for (int ni = 0; ni < 4; ++ni)                             \
    acc[mi][ni] = MF(ahi[mi], blo[ni], acc[mi][ni]);                           \
  PH_END();                                                                    \
  /* ph4: hi*lo mf4-7 */                                                       \
  PH_TOP();                                                                    \
  if (STAGE) STG2((u) + 1, nbuf, 1);                                           \
  PH_MID();                                                                    \
  _Pragma("unroll") for (int mi = 0; mi < 4; ++mi)                             \
  _Pragma("unroll") for (int ni = 0; ni < 4; ++ni)                             \
    acc[4 + mi][ni] = MF(ahi[4 + mi], blo[ni], acc[4 + mi][ni]);               \
  PH_END();                                                                    \
  /* ph5: lo*hi mf0-3 */                                                       \
  WV5; PH_TOP();                                                               \
  _Pragma("unroll") for (int q = 0; q < 4; ++q) alo[q] = ds128(vA + 16384 + q * 1024); \
  PH_MID();                                                                    \
  _Pragma("unroll") for (int mi = 0; mi < 4; ++mi)                             \
  _Pragma("unroll") for (int ni = 0; ni < 4; ++ni)                             \
    acc[mi][ni] = MF(alo[mi], bhi[ni], acc[mi][ni]);                           \
  PH_END();                                                                    \
  /* ph6: lo*hi mf4-7 */                                                       \
  PH_TOP();                                                                    \
  _Pragma("unroll") for (int q = 0; q < 4; ++q) alo[q] = ds128(vA + 16384 + (4 + q) * 1024); \
  PH_MID();                                                                    \
  _Pragma("unroll") for (int mi = 0; mi < 4; ++mi)                             \
  _Pragma("unroll") for (int ni = 0; ni < 4; ++ni)                             \
    acc[4 + mi][ni] = MF(alo[mi], bhi[ni], acc[4 + mi][ni]);                   \
  PH_END();                                                                    \
  vA ^= 65536u; vB ^= 65536u;                                                  \
} while (0)

  STG2(0, 0, 0); STG2(0, 0, 2); STG2(0, 0, 3); STG2(0, 0, 1);

  unsigned nbuf = 65536u;
  for (int u = 0; u < nkt - 1; ++u) {
    TILE(u, WAITV(4), WAITV(6), WAITV(8), 1);
    nbuf ^= 65536u;
  }
  TILE(nkt - 1, WAITV(4), WAITV(2), WAITV(0), 0);
#undef TILE
#undef PH_TOP
#undef PH_MID
#undef PH_END

  const size_t cb = (size_t)b * sC;
  const int mB = m0 + wm * 128 + ((lane >> 4) << 2);
  const int nB = n0 + wn * 64 + (lane & 15);
#pragma unroll
  for (int mf = 0; mf < 8; ++mf)
#pragma unroll
    for (int j = 0; j < 4; ++j) {
      int m = mB + mf * 16 + j;
#pragma unroll
      for (int nf = 0; nf < 4; ++nf) {
        int n = nB + nf * 16;
        float v = acc[mf][nf][j];
        size_t o = (size_t)m * N + n;
        if (EPI == 0) {
          v = (v + bias[n] + addend[o]) * scale;
          unsigned short hb = f2bf(v);
          outHi[o] = hb;
          outLo[o] = f2bf(v - bf2f(hb));
        } else {
          outF[cb + o] = v;
        }
      }
    }
}

// ====== split (hi/lo) GEMM, 128x128 tile, 256 threads, BK=32, 3 phases, 1-buffer 32KB ======
// Residency-optimized scores core: ~3 blocks/CU (4-wave blocks, 32KB LDS, <=170 regs).
// Regions: Ah@0 (8K), Al@8K, Bh@16K, Bl@24K. 2 stage units each.
// Stage: ph1 -> Al[u]; ph2 -> Bh[u+1], Ah[u+1]; ph3 -> Bl[u+1].
// vmcnt (2-unit regions): steady (2)/(2)/(4); last tile (2)/(2)/(0). Prologue Bh,Ah,Bl.
template <int EPI>
__global__ __launch_bounds__(256, 3) void k_split128(
    const unsigned short* __restrict__ Ah, const unsigned short* __restrict__ Al,
    const unsigned short* __restrict__ Bh, const unsigned short* __restrict__ Bl,
    int N, int K, long sA, long sB, long sC,
    const float* __restrict__ bias, const float* __restrict__ addend,
    float* __restrict__ outF, unsigned short* __restrict__ outHi,
    unsigned short* __restrict__ outLo, float scale, const int* __restrict__ npad) {
  extern __shared__ char lds[];
  const int tid = threadIdx.x, wave = tid >> 6, lane = tid & 63;
  int L = xcd_logical();
  const int n0 = (L % gridDim.x) * 128;
  int tmpL = L / gridDim.x;
  const int m0 = (tmpL % gridDim.y) * 128;
  const int b = tmpL / gridDim.y;
  if (npad && n0 >= npad[b]) return;
  const int wm = wave >> 1, wn = wave & 1;   // 2x2 waves; wave owns 64x64
  const unsigned short* gb[4];
  gb[0] = Ah + (size_t)b * sA + (size_t)m0 * K;
  gb[1] = Al + (size_t)b * sA + (size_t)m0 * K;
  gb[2] = Bh + (size_t)b * sB + (size_t)n0 * K;
  gb[3] = Bl + (size_t)b * sB + (size_t)n0 * K;
  const unsigned ldsB = ldsoff(lds);

  int soff[2];
#pragma unroll
  for (int s = 0; s < 2; ++s) {
    int l = swzi(s * 4096 + tid * 16);
    soff[s] = (l >> 6) * K + ((l >> 4) & 3) * 8;
  }
  const int aR = wm * 64 + (lane & 15);
  const int bR = wn * 64 + (lane & 15);
  const int kB = (lane >> 4) * 16;
  const int nkt = K >> 5;

  const unsigned vA = ldsB + (unsigned)swzi(aR * 64 + kB);          // Ah; Al = +8192
  const unsigned vB = ldsB + 16384u + (unsigned)swzi(bR * 64 + kB); // Bh; Bl = +8192

  f32x4 acc[4][4] = {};

  auto STG = [&](int t, int r) {   // region r, 2 units
    char* dst = lds + r * 8192 + tid * 16;
    const unsigned short* g = gb[r] + (size_t)t * 32;
    gload16(g + soff[0], dst);
    gload16(g + soff[1], dst + 4096);
  };

#define TILE3(u, WV1, WV2, WV3, STAGE) do {                                    \
  short8 ahi[4], bhi[4], blo[4], alo[4];                                       \
  /* ph1: hi*hi */                                                             \
  WV1; BAR();                                                                  \
  _Pragma("unroll") for (int q = 0; q < 4; ++q) bhi[q] = ds128(vB + q * 1024); \
  _Pragma("unroll") for (int q = 0; q < 4; ++q) ahi[q] = ds128(vA + q * 1024); \
  STG(u, 1);                                                                   \
  BAR(); WAITL(0); SCH0(); PRIO1();                                            \
  _Pragma("unroll") for (int mi = 0; mi < 4; ++mi)                             \
  _Pragma("unroll") for (int ni = 0; ni < 4; ++ni)                             \
    acc[mi][ni] = MF(ahi[mi], bhi[ni], acc[mi][ni]);                           \
  PRIO0(); SCH0();                                                             \
  /* ph2: hi*lo */                                                             \
  WV2; BAR();                                                                  \
  _Pragma("unroll") for (int q = 0; q < 4; ++q) blo[q] = ds128(vB + 8192 + q * 1024); \
  if (STAGE) { STG((u) + 1, 2); STG((u) + 1, 0); }                             \
  BAR(); WAITL(0); SCH0(); PRIO1();                                            \
  _Pragma("unroll") for (int mi = 0; mi < 4; ++mi)                             \
  _Pragma("unroll") for (int ni = 0; ni < 4; ++ni)                             \
    acc[mi][ni] = MF(ahi[mi], blo[ni], acc[mi][ni]);                           \
  PRIO0(); SCH0();                                                             \
  /* ph3: lo*hi */                                                             \
  WV3; BAR();                                                                  \
  _Pragma("unroll") for (int q = 0; q < 4; ++q) alo[q] = ds128(vA + 8192 + q * 1024); \
  if (STAGE) STG((u) + 1, 3);                                                  \
  BAR(); WAITL(0); SCH0(); PRIO1();                                            \
  _Pragma("unroll") for (int mi = 0; mi < 4; ++mi)                             \
  _Pragma("unroll") for (int ni = 0; ni < 4; ++ni)                             \
    acc[mi][ni] = MF(alo[mi], bhi[ni], acc[mi][ni]);                           \
  PRIO0(); SCH0();                                                             \
} while (0)

  // prologue: Bh[0], Ah[0], Bl[0] (2 units each -> 6 outstanding)
  STG(0, 2); STG(0, 0); STG(0, 3);

  for (int u = 0; u < nkt - 1; ++u)
    TILE3(u, WAITV(2), WAITV(2), WAITV(4), 1);
  TILE3(nkt - 1, WAITV(2), WAITV(2), WAITV(0), 0);
#undef TILE3

  const size_t cb = (size_t)b * sC;
  const int mB = m0 + wm * 64 + ((lane >> 4) << 2);
  const int nB = n0 + wn * 64 + (lane & 15);
#pragma unroll
  for (int mf = 0; mf < 4; ++mf)
#pragma unroll
    for (int j = 0; j < 4; ++j) {
      int m = mB + mf * 16 + j;
#pragma unroll
      for (int nf = 0; nf < 4; ++nf) {
        int n = nB + nf * 16;
        float v = acc[mf][nf][j];
        size_t o = (size_t)m * N + n;
        if (EPI == 0) {
          v = (v + bias[n] + addend[o]) * scale;
          unsigned short hb = f2bf(v);
          outHi[o] = hb;
          outLo[o] = f2bf(v - bf2f(hb));
        } else {
          outF[cb + o] = v;
        }
      }
    }
}

// -------- softmax: compact scores row -> full f32 attn row + compact bf16 attn --------
__global__ __launch_bounds__(256) void k_softmax(const float* __restrict__ scores_c,
    float* __restrict__ attn, unsigned short* __restrict__ attn_bc,
    const int* __restrict__ mask, const int* __restrict__ pfx,
    const int* __restrict__ cnt, const int* __restrict__ kpad) {
  __shared__ float sl[NMAX];
  __shared__ float red[8];
  long r = blockIdx.x;
  int b = (int)(r >> 11);
  int t = threadIdx.x;
  int cb = cnt[b], kp = kpad[b];
  const float* srow = scores_c + r * (long)NMAX;
  for (int i = t; i < cb; i += 256) sl[i] = srow[i];
  __syncthreads();
  int base = t * 8;
  const int* mrow = mask + (size_t)b * SS;
  int4 m0i = *(const int4*)(mrow + base);
  int4 m1i = *(const int4*)(mrow + base + 4);
  int mm[8] = {m0i.x, m0i.y, m0i.z, m0i.w, m1i.x, m1i.y, m1i.z, m1i.w};
  const int* prow = pfx + (size_t)b * SS;
  int4 p0i = *(const int4*)(prow + base);
  int4 p1i = *(const int4*)(prow + base + 4);
  int pp[8] = {p0i.x, p0i.y, p0i.z, p0i.w, p1i.x, p1i.y, p1i.z, p1i.w};
  float v[8];
#pragma unroll
  for (int j = 0; j < 8; ++j) v[j] = mm[j] ? -INFINITY : sl[pp[j]];
  float mx = v[0];
#pragma unroll
  for (int j = 1; j < 8; ++j) mx = fmaxf(mx, v[j]);
#pragma unroll
  for (int off = 32; off; off >>= 1) mx = fmaxf(mx, __shfl_xor(mx, off));
  int wv = t >> 6, ln = t & 63;
  if (ln == 0) red[wv] = mx;
  __syncthreads();
  mx = fmaxf(fmaxf(red[0], red[1]), fmaxf(red[2], red[3]));
  float sum = 0.f;
#pragma unroll
  for (int j = 0; j < 8; ++j) { v[j] = __expf(v[j] - mx); sum += v[j]; }
#pragma unroll
  for (int off = 32; off; off >>= 1) sum += __shfl_xor(sum, off);
  if (ln == 0) red[4 + wv] = sum;
  __syncthreads();
  sum = (red[4] + red[5]) + (red[6] + red[7]);
  float inv = 1.0f / sum;
#pragma unroll
  for (int j = 0; j < 8; ++j) v[j] *= inv;
  float* arow = attn + r * (long)SS;
  float4 w0; w0.x = v[0]; w0.y = v[1]; w0.z = v[2]; w0.w = v[3];
  float4 w1; w1.x = v[4]; w1.y = v[5]; w1.z = v[6]; w1.w = v[7];
  *(float4*)(arow + base) = w0;
  *(float4*)(arow + base + 4) = w1;
  __syncthreads();          // sl reads done; reuse for compact attn
#pragma unroll
  for (int j = 0; j < 8; ++j) if (!mm[j]) sl[pp[j]] = v[j];
  __syncthreads();
  unsigned short* brow = attn_bc + r * (long)NMAX;
  for (int i = t; i < kp; i += 256) brow[i] = f2bf(i < cb ? sl[i] : 0.f);
}

extern "C" void kernel_launch(void* const* d_in, const int* in_sizes, int n_in,
                              void* d_out, int out_size, void* d_ws, size_t ws_size,
                              hipStream_t stream) {
  (void)in_sizes; (void)n_in; (void)out_size; (void)ws_size;
  const float* x     = (const float*)d_in[0];
  const float* tgt   = (const float*)d_in[1];
  const float* enca  = (const float*)d_in[2];
  const float* encb  = (const float*)d_in[3];
  const int*   mask  = (const int*)d_in[4];
  const float* w_in  = (const float*)d_in[5];
  const float* b_in  = (const float*)d_in[6];
  const float* w_out = (const float*)d_in[7];
  const float* b_out = (const float*)d_in[8];

  float* out  = (float*)d_out;                       // [B,T,C]
  float* attn = out + (size_t)NB * TT * CC;          // [B,T,S]

  char* ws = (char*)d_ws;
  // liveness-phased layout (NMAX=1280)
  float*          scores_c = (float*)(ws + 0);                    // [0, 83886080)
  unsigned short* x_hi   = (unsigned short*)(ws + 0);             // dead before scores
  unsigned short* x_lo   = (unsigned short*)(ws + 33554432L);
  unsigned short* pv     = (unsigned short*)(ws + 0);             // after softmax
  unsigned short* h_hi   = (unsigned short*)(ws + 83886080L);
  unsigned short* h_lo   = (unsigned short*)(ws + 117440512L);
  unsigned short* attn_bc= (unsigned short*)(ws + 83886080L);     // after scores (h dead)
  unsigned short* a_tc_hi= (unsigned short*)(ws + 150994944L);
  unsigned short* a_tc_lo= (unsigned short*)(ws + 171966464L);
  unsigned short* b_tc   = (unsigned short*)(ws + 192937984L);
  unsigned short* w_in_hi= (unsigned short*)(ws + 213909504L);
  unsigned short* w_in_lo= (unsigned short*)(ws + 216006656L);
  unsigned short* w_out_b= (unsigned short*)(ws + 218103808L);
  int* idx  = (int*)(ws + 220200960L);
  int* pfx  = (int*)(ws + 220266496L);
  int* cnt  = (int*)(ws + 220332032L);
  int* kpad = (int*)(ws + 220332096L);

  hipFuncSetAttribute(reinterpret_cast<const void*>(&k_gemm8<2>),
                      hipFuncAttributeMaxDynamicSharedMemorySize, 131072);
  hipFuncSetAttribute(reinterpret_cast<const void*>(&k_gemm8<3>),
                      hipFuncAttributeMaxDynamicSharedMemorySize, 131072);
  hipFuncSetAttribute(reinterpret_cast<const void*>(&k_split6<0>),
                      hipFuncAttributeMaxDynamicSharedMemorySize, 131072);
  hipFuncSetAttribute(reinterpret_cast<const void*>(&k_split128<1>),
                      hipFuncAttributeMaxDynamicSharedMemorySize, 32768);

  dim3 blk(256), blk512(512);
  const float S05 = 0.70710678118654752f;

  k_scan<<<NB, blk, 0, stream>>>(mask, idx, pfx, cnt, kpad);
  k_split<<<2048, blk, 0, stream>>>(x, x_hi, x_lo, (long)NB * TT * CC / 4);
  k_split<<<512, blk, 0, stream>>>(w_in, w_in_hi, w_in_lo, (long)EE * CC / 4);
  k_conv<<<512, blk, 0, stream>>>(w_out, w_out_b, (long)CC * EE / 4);
  k_ta<<<dim3(NMAX / 64, EE / 64, NB), blk, 0, stream>>>(enca, idx, cnt, a_tc_hi, a_tc_lo);
  k_tb<<<dim3(NMAX / 64, EE / 64, NB), blk, 0, stream>>>(encb, idx, cnt, b_tc);

  // GEMM1: h = (x @ w_in^T + b_in + tgt) * sqrt(0.5). 6-phase 256^2 core, 256 blocks.
  k_split6<0><<<dim3(EE / 256, (NB * TT) / 256, 1), blk512, 131072, stream>>>(
      x_hi, x_lo, w_in_hi, w_in_lo, EE, CC, 0, 0, 0,
      b_in, tgt, nullptr, h_hi, h_lo, S05, nullptr);

  // scores_c = h @ a_tc (compact, batched). 128x128 3-block/CU core, 1280 blocks.
  k_split128<1><<<dim3(NMAX / 128, TT / 128, NB), blk, 32768, stream>>>(
      h_hi, h_lo, a_tc_hi, a_tc_lo, NMAX, EE,
      (long)TT * EE, (long)NMAX * EE, (long)TT * NMAX,
      nullptr, nullptr, scores_c, nullptr, nullptr, 1.0f, kpad);

  // masked softmax on compact domain; writes full attn (f32) + compact attn_bc (bf16)
  k_softmax<<<NB * TT, blk, 0, stream>>>(scores_c, attn, attn_bc, mask, pfx, cnt, kpad);

  // pv = (attn_bc @ b_tc) * sqrt(S), dynamic K = kpad[b], bf16 out
  k_gemm8<2><<<dim3(EE / 256, TT / 256, NB), blk512, 131072, stream>>>(
      attn_bc, b_tc, EE, NMAX, kpad,
      (long)TT * NMAX, (long)EE * NMAX, (long)TT * EE,
      nullptr, nullptr, nullptr, pv, 45.254833995939045f);

  // out = (pv @ w_out^T + b_out + x) * sqrt(0.5)
  k_gemm8<3><<<dim3(CC / 256, (NB * TT) / 256, 1), blk512, 131072, stream>>>(
      pv, w_out_b, CC, EE, nullptr, 0, 0, 0,
      b_out, x, out, nullptr, S05);
}

// Round 16
// 459.972 us; speedup vs baseline: 1.0776x; 1.0436x over previous
//
#include <hip/hip_runtime.h>
#include <hip/hip_bf16.h>
#include <math.h>

#define NB 8
#define TT 2048
#define SS 2048
#define CC 1024
#define EE 1024
#define NMAX 1280

typedef __attribute__((ext_vector_type(8))) short short8;
typedef __attribute__((ext_vector_type(4))) float f32x4;

__device__ __forceinline__ unsigned short f2bf(float f) {
  unsigned u = __builtin_bit_cast(unsigned, f);
  u += 0x7fffu + ((u >> 16) & 1u);          // RNE
  return (unsigned short)(u >> 16);
}
__device__ __forceinline__ float bf2f(unsigned short h) {
  unsigned u = ((unsigned)h) << 16;
  return __builtin_bit_cast(float, u);
}
__device__ __forceinline__ void gload16(const void* g, void* l) {
  __builtin_amdgcn_global_load_lds((const __attribute__((address_space(1))) void*)g,
                                   (__attribute__((address_space(3))) void*)l, 16, 0, 0);
}
__device__ __forceinline__ unsigned ldsoff(const void* p) {
  return (unsigned)(size_t)(const __attribute__((address_space(3))) char*)p;
}
__device__ __forceinline__ short8 ds128(unsigned off) {
  short8 r;
  asm volatile("ds_read_b128 %0, %1" : "=v"(r) : "v"(off));
  return r;
}
// XOR swizzle: bits 4-6 ^= bits 7-9 (involution)
__device__ __forceinline__ int swzi(int x) { return x ^ (((x >> 7) & 7) << 4); }

#define WAITV(N) asm volatile("s_waitcnt vmcnt(" #N ")" ::: "memory")
#define WAITL(N) asm volatile("s_waitcnt lgkmcnt(" #N ")" ::: "memory")
#define BAR() __builtin_amdgcn_s_barrier()
#define SCH0() __builtin_amdgcn_sched_barrier(0)
#define PRIO1() __builtin_amdgcn_s_setprio(1)
#define PRIO0() __builtin_amdgcn_s_setprio(0)
#define MF(a_, b_, c_) __builtin_amdgcn_mfma_f32_16x16x32_bf16(a_, b_, c_, 0, 0, 0)

// chunked bijective XCD swizzle (requires nwg % 8 == 0; all our grids qualify)
__device__ __forceinline__ int xcd_logical() {
  int gx = gridDim.x, gy = gridDim.y, gz = gridDim.z;
  int pid = blockIdx.x + gx * (blockIdx.y + gy * blockIdx.z);
  int q = (gx * gy * gz) >> 3;
  return (pid & 7) * q + (pid >> 3);
}

// ---------------- mask scan: per batch, compaction tables ----------------
__global__ __launch_bounds__(256) void k_scan(const int* __restrict__ mask,
    int* __restrict__ idx, int* __restrict__ pfx, int* __restrict__ cnt,
    int* __restrict__ kpad) {
  __shared__ int cs[256];
  int b = blockIdx.x, t = threadIdx.x;
  const int* mrow = mask + (size_t)b * SS;
  int4 a = ((const int4*)mrow)[t * 2];
  int4 c2 = ((const int4*)mrow)[t * 2 + 1];
  int mm[8] = {a.x, a.y, a.z, a.w, c2.x, c2.y, c2.z, c2.w};
  int c = 0;
#pragma unroll
  for (int j = 0; j < 8; ++j) c += (mm[j] == 0);
  cs[t] = c;
  __syncthreads();
  if (t == 0) {
    int run = 0;
    for (int i = 0; i < 256; ++i) { int tmp = cs[i]; cs[i] = run; run += tmp; }
    cnt[b] = run;
    int kp = (run + 127) & ~127;
    if (kp > NMAX) kp = NMAX;
    kpad[b] = kp;
  }
  __syncthreads();
  int base = cs[t];
#pragma unroll
  for (int j = 0; j < 8; ++j) {
    int s = t * 8 + j;
    pfx[(size_t)b * SS + s] = base;
    if (mm[j] == 0) { idx[(size_t)b * SS + base] = s; base++; }
  }
}

// ---------------- split f32 -> bf16 hi/lo ----------------
__global__ __launch_bounds__(256) void k_split(const float* __restrict__ in,
    unsigned short* __restrict__ hi, unsigned short* __restrict__ lo, long n4) {
  long i = (long)blockIdx.x * blockDim.x + threadIdx.x;
  long stride = (long)gridDim.x * blockDim.x;
  for (; i < n4; i += stride) {
    float4 v = ((const float4*)in)[i];
    float f[4] = {v.x, v.y, v.z, v.w};
    unsigned short hh[4], ll[4];
#pragma unroll
    for (int j = 0; j < 4; ++j) {
      hh[j] = f2bf(f[j]);
      ll[j] = f2bf(f[j] - bf2f(hh[j]));
    }
    ushort4 h; h.x = hh[0]; h.y = hh[1]; h.z = hh[2]; h.w = hh[3];
    ushort4 l; l.x = ll[0]; l.y = ll[1]; l.z = ll[2]; l.w = ll[3];
    ((ushort4*)hi)[i] = h;
    ((ushort4*)lo)[i] = l;
  }
}

// ---------------- f32 -> bf16 convert ----------------
__global__ __launch_bounds__(256) void k_conv(const float* __restrict__ in,
    unsigned short* __restrict__ out, long n4) {
  long i = (long)blockIdx.x * blockDim.x + threadIdx.x;
  long stride = (long)gridDim.x * blockDim.x;
  for (; i < n4; i += stride) {
    float4 v = ((const float4*)in)[i];
    ushort4 h; h.x = f2bf(v.x); h.y = f2bf(v.y); h.z = f2bf(v.z); h.w = f2bf(v.w);
    ((ushort4*)out)[i] = h;
  }
}

// ------- enc_a compact transpose, coalesced-read version -------
// Reads contiguous [64e x 64s] tiles (float4 along s); scatters on the WRITE side:
// unmasked s -> compact row pfx[s] (consecutive unmasked s = consecutive rows, dense).
// Padded rows [cnt,kpad) are NOT written: garbage there only affects scores columns
// n>=cnt, which softmax never reads; attn_bc zero-pad for PV happens in k_softmax.
__global__ __launch_bounds__(256) void k_ta(const float* __restrict__ enca,
    const int* __restrict__ mask, const int* __restrict__ pfx,
    unsigned short* __restrict__ hi, unsigned short* __restrict__ lo) {
  __shared__ float tile[64][65];
  int b = blockIdx.z, s0 = blockIdx.x * 64, e0 = blockIdx.y * 64;
  const float* src = enca + (size_t)b * EE * SS;
  int t = threadIdx.x;
  int er = t >> 4;             // 0..15
  int slc = (t & 15) * 4;      // 0..60
#pragma unroll
  for (int i = 0; i < 4; ++i) {
    int e = er + i * 16;
    float4 v = *(const float4*)(src + (size_t)(e0 + e) * SS + s0 + slc);
    tile[e][slc] = v.x; tile[e][slc + 1] = v.y;
    tile[e][slc + 2] = v.z; tile[e][slc + 3] = v.w;
  }
  __syncthreads();
  int sl = t >> 2;             // 0..63
  int eq = (t & 3) * 16;       // 0,16,32,48
  int s = s0 + sl;
  if (mask[(size_t)b * SS + s] == 0) {
    int sc = pfx[(size_t)b * SS + s];
    size_t rb = (size_t)b * NMAX * EE + (size_t)sc * EE + e0 + eq;
#pragma unroll
    for (int i = 0; i < 4; ++i) {
      unsigned short hh[4], ll[4];
#pragma unroll
      for (int j = 0; j < 4; ++j) {
        float f = tile[eq + i * 4 + j][sl];
        hh[j] = f2bf(f);
        ll[j] = f2bf(f - bf2f(hh[j]));
      }
      ushort4 h4; h4.x = hh[0]; h4.y = hh[1]; h4.z = hh[2]; h4.w = hh[3];
      ushort4 l4; l4.x = ll[0]; l4.y = ll[1]; l4.z = ll[2]; l4.w = ll[3];
      *(ushort4*)(hi + rb + i * 4) = h4;
      *(ushort4*)(lo + rb + i * 4) = l4;
    }
  }
}

// ------- enc_b compact transpose: b_tc[b][e][sc] = enc_b[b][idx[sc]][e], bf16 -------
__global__ __launch_bounds__(256) void k_tb(const float* __restrict__ encb,
    const int* __restrict__ idx, const int* __restrict__ cnt,
    unsigned short* __restrict__ out) {
  __shared__ float tile[64][65];
  int b = blockIdx.z, sc0 = blockIdx.x * 64, e0 = blockIdx.y * 64;
  int cb = cnt[b];
  const float* src = encb + (size_t)b * SS * EE;
  int t = threadIdx.x, tr = t >> 4, tc = (t & 15) * 4;
#pragma unroll
  for (int i = 0; i < 4; ++i) {
    int r = tr + i * 16;   // sc-local
    int sc = sc0 + r;
    int sidx = (sc < cb) ? idx[(size_t)b * SS + sc] : -1;
    float4 v;
    if (sidx >= 0) v = *(const float4*)(src + (size_t)sidx * EE + e0 + tc);
    else { v.x = v.y = v.z = v.w = 0.f; }
    tile[r][tc] = v.x; tile[r][tc + 1] = v.y; tile[r][tc + 2] = v.z; tile[r][tc + 3] = v.w;
  }
  __syncthreads();
  size_t ob = (size_t)b * EE * NMAX;
#pragma unroll
  for (int i = 0; i < 4; ++i) {
    int c = tr + i * 16;   // e-local
    unsigned short hh[4];
#pragma unroll
    for (int j = 0; j < 4; ++j) hh[j] = f2bf(tile[tc + j][c]);
    ushort4 h; h.x = hh[0]; h.y = hh[1]; h.z = hh[2]; h.w = hh[3];
    *(ushort4*)(out + ob + (size_t)(e0 + c) * NMAX + sc0 + tc) = h;
  }
}

// ================= plain bf16 GEMM, 256x256 tile, BK=64, 4 phases, dynamic K ==============
template <int EPI>
__global__ __launch_bounds__(512, 2) void k_gemm8(
    const unsigned short* __restrict__ A, const unsigned short* __restrict__ B,
    int N, int KROW, const int* __restrict__ kdyn, long sA, long sB, long sC,
    const float* __restrict__ bias, const float* __restrict__ addend,
    float* __restrict__ outF, unsigned short* __restrict__ outH, float scale) {
  extern __shared__ char lds[];
  const int tid = threadIdx.x, wave = tid >> 6, lane = tid & 63;
  int L = xcd_logical();
  const int n0 = (L % gridDim.x) * 256;
  int tmpL = L / gridDim.x;
  const int m0 = (tmpL % gridDim.y) * 256;
  const int b = tmpL / gridDim.y;
  const int KD = kdyn ? kdyn[b] : KROW;
  const int wm = wave >> 2, wn = wave & 3;
  const unsigned short* gA = A + (size_t)b * sA + (size_t)m0 * KROW;
  const unsigned short* gB = B + (size_t)b * sB + (size_t)n0 * KROW;
  const unsigned ldsB = ldsoff(lds);

  int srow[2], sk8[2];
#pragma unroll
  for (int s = 0; s < 2; ++s) {
    int l = swzi((s * 512 + tid) * 16);
    srow[s] = l >> 6;
    sk8[s] = (l >> 4) & 3;
  }
  const int aR = wm * 128 + (lane & 15);
  const int bR = wn * 64 + (lane & 15);
  const int kB = (lane >> 4) * 16;
  const int nkt = KD >> 6;

  f32x4 acc[8][4] = {};

  auto STG = [&](int t, int tensor, int ks) {
    const unsigned short* g = tensor ? gB : gA;
    char* dst = lds + (t & 1) * 65536 + tensor * 32768 + ks * 16384 + wave * 1024;
    size_t gk = (size_t)t * 64 + ks * 32;
#pragma unroll
    for (int s = 0; s < 2; ++s)
      gload16(g + ((size_t)srow[s] * KROW + gk + sk8[s] * 8), dst + s * 8192);
  };
  auto RA = [&](int t, int ks, int mf) {
    int lin = (aR + mf * 16) * 64 + kB;
    return ds128(ldsB + (t & 1) * 65536 + ks * 16384 + swzi(lin));
  };
  auto RB = [&](int t, int ks, int nf) {
    int lin = (bR + nf * 16) * 64 + kB;
    return ds128(ldsB + (t & 1) * 65536 + 32768 + ks * 16384 + swzi(lin));
  };

  STG(0, 1, 0); STG(0, 0, 0); STG(0, 0, 1); STG(0, 1, 1);
  if (nkt > 1) { STG(1, 1, 0); STG(1, 0, 0); }

  for (int u = 0; u < nkt; ++u) {
    if (u + 1 < nkt) { WAITV(8); } else { WAITV(0); }
    BAR();
    short8 bf[4], af[4];
#pragma unroll
    for (int nf = 0; nf < 4; ++nf) bf[nf] = RB(u, 0, nf);
#pragma unroll
    for (int mf = 0; mf < 4; ++mf) af[mf] = RA(u, 0, mf);
    if (u + 1 < nkt) { STG(u + 1, 0, 1); STG(u + 1, 1, 1); }
    BAR(); WAITL(0); SCH0(); PRIO1();
#pragma unroll
    for (int mf = 0; mf < 4; ++mf)
#pragma unroll
      for (int nf = 0; nf < 4; ++nf) acc[mf][nf] = MF(af[mf], bf[nf], acc[mf][nf]);
    PRIO0(); SCH0(); BAR();
#pragma unroll
    for (int mf = 0; mf < 4; ++mf) af[mf] = RA(u, 0, mf + 4);
    if (u + 2 < nkt) STG(u + 2, 1, 0);
    BAR(); WAITL(0); SCH0(); PRIO1();
#pragma unroll
    for (int mf = 0; mf < 4; ++mf)
#pragma unroll
      for (int nf = 0; nf < 4; ++nf) acc[mf + 4][nf] = MF(af[mf], bf[nf], acc[mf + 4][nf]);
    PRIO0(); SCH0();
    if (u + 2 < nkt) { WAITV(10); } else if (u + 1 < nkt) { WAITV(8); } else { WAITV(0); }
    BAR();
#pragma unroll
    for (int nf = 0; nf < 4; ++nf) bf[nf] = RB(u, 1, nf);
#pragma unroll
    for (int mf = 0; mf < 4; ++mf) af[mf] = RA(u, 1, mf);
    if (u + 2 < nkt) STG(u + 2, 0, 0);
    BAR(); WAITL(0); SCH0(); PRIO1();
#pragma unroll
    for (int mf = 0; mf < 4; ++mf)
#pragma unroll
      for (int nf = 0; nf < 4; ++nf) acc[mf][nf] = MF(af[mf], bf[nf], acc[mf][nf]);
    PRIO0(); SCH0(); BAR();
#pragma unroll
    for (int mf = 0; mf < 4; ++mf) af[mf] = RA(u, 1, mf + 4);
    BAR(); WAITL(0); SCH0(); PRIO1();
#pragma unroll
    for (int mf = 0; mf < 4; ++mf)
#pragma unroll
      for (int nf = 0; nf < 4; ++nf) acc[mf + 4][nf] = MF(af[mf], bf[nf], acc[mf + 4][nf]);
    PRIO0(); SCH0(); BAR();
  }

  const size_t cb = (size_t)b * sC;
  const int mB = m0 + wm * 128 + ((lane >> 4) << 2);
  const int nB = n0 + wn * 64 + (lane & 15);
#pragma unroll
  for (int mf = 0; mf < 8; ++mf)
#pragma unroll
    for (int j = 0; j < 4; ++j) {
      int m = mB + mf * 16 + j;
#pragma unroll
      for (int nf = 0; nf < 4; ++nf) {
        int n = nB + nf * 16;
        float v = acc[mf][nf][j];
        size_t o = (size_t)m * N + n;
        if (EPI == 2) outH[cb + o] = f2bf(v * scale);
        else outF[o] = (v + bias[n] + addend[o]) * scale;
      }
    }
}

// ============ split (hi/lo) GEMM, 256x256 tile, BK=32, 3 products, 6 sub-phases ============
// R5/R9-proven schedule (52% MfmaUtil), double-buffered 128KB. Used for GEMM1.
template <int EPI>
__global__ __launch_bounds__(512, 2) void k_split6(
    const unsigned short* __restrict__ Ah, const unsigned short* __restrict__ Al,
    const unsigned short* __restrict__ Bh, const unsigned short* __restrict__ Bl,
    int N, int K, long sA, long sB, long sC,
    const float* __restrict__ bias, const float* __restrict__ addend,
    float* __restrict__ outF, unsigned short* __restrict__ outHi,
    unsigned short* __restrict__ outLo, float scale, const int* __restrict__ npad) {
  extern __shared__ char lds[];
  const int tid = threadIdx.x, wave = tid >> 6, lane = tid & 63;
  int L = xcd_logical();
  const int n0 = (L % gridDim.x) * 256;
  int tmpL = L / gridDim.x;
  const int m0 = (tmpL % gridDim.y) * 256;
  const int b = tmpL / gridDim.y;
  if (npad && n0 >= npad[b]) return;
  const int wm = wave >> 2, wn = wave & 3;
  const unsigned short* gb[4];
  gb[0] = Ah + (size_t)b * sA + (size_t)m0 * K;
  gb[1] = Al + (size_t)b * sA + (size_t)m0 * K;
  gb[2] = Bh + (size_t)b * sB + (size_t)n0 * K;
  gb[3] = Bl + (size_t)b * sB + (size_t)n0 * K;
  const unsigned ldsB = ldsoff(lds);

  int soff[2];
#pragma unroll
  for (int s = 0; s < 2; ++s) {
    int l = swzi((s * 512 + tid) * 16);
    soff[s] = (l >> 6) * K + ((l >> 4) & 3) * 8;
  }
  const int aR = wm * 128 + (lane & 15);
  const int bR = wn * 64 + (lane & 15);
  const int kB = (lane >> 4) * 16;
  const int nkt = K >> 5;

  unsigned vA = ldsB + (unsigned)swzi(aR * 64 + kB);
  unsigned vB = ldsB + (unsigned)swzi(bR * 64 + kB);

  f32x4 acc[8][4] = {};

  auto STG2 = [&](int t, unsigned bufbase, int region) {
    char* dst = lds + bufbase + region * 16384 + tid * 16;
    const unsigned short* g = gb[region] + (size_t)t * 32;
#pragma unroll
    for (int s = 0; s < 2; ++s)
      gload16(g + soff[s], dst + s * 8192);
  };

#define PH_TOP() BAR()
#define PH_MID() BAR(); WAITL(0); SCH0(); PRIO1()
#define PH_END() PRIO0(); SCH0()

#define TILE(u, WV1, WV3, WV5, STAGE) do {                                     \
  short8 ahi[8], bhi[4], blo[4], alo[4];                                       \
  /* ph1: hi*hi mf0-3 */                                                       \
  WV1; PH_TOP();                                                               \
  _Pragma("unroll") for (int q = 0; q < 4; ++q) bhi[q] = ds128(vB + 32768 + q * 1024); \
  _Pragma("unroll") for (int q = 0; q < 4; ++q) ahi[q] = ds128(vA + q * 1024); \
  if (STAGE) STG2((u) + 1, nbuf, 0);                                           \
  PH_MID();                                                                    \
  _Pragma("unroll") for (int mi = 0; mi < 4; ++mi)                             \
  _Pragma("unroll") for (int ni = 0; ni < 4; ++ni)                             \
    acc[mi][ni] = MF(ahi[mi], bhi[ni], acc[mi][ni]);                           \
  PH_END();                                                                    \
  /* ph2: hi*hi mf4-7 */                                                       \
  PH_TOP();                                                                    \
  _Pragma("unroll") for (int q = 0; q < 4; ++q) ahi[4 + q] = ds128(vA + (4 + q) * 1024); \
  if (STAGE) STG2((u) + 1, nbuf, 2);                                           \
  PH_MID();                                                                    \
  _Pragma("unroll") for (int mi = 0; mi < 4; ++mi)                             \
  _Pragma("unroll") for (int ni = 0; ni < 4; ++ni)                             \
    acc[4 + mi][ni] = MF(ahi[4 + mi], bhi[ni], acc[4 + mi][ni]);               \
  PH_END();                                                                    \
  /* ph3: hi*lo mf0-3 */                                                       \
  WV3; PH_TOP();                                                               \
  _Pragma("unroll") for (int q = 0; q < 4; ++q) blo[q] = ds128(vB + 49152 + q * 1024); \
  if (STAGE) STG2((u) + 1, nbuf, 3);                                           \
  PH_MID();                                                                    \
  _Pragma("unroll") for (int mi = 0; mi < 4; ++mi)                             \
  _Pragma("unroll") for (int ni = 0; ni < 4; ++ni)                             \
    acc[mi][ni] = MF(ahi[mi], blo[ni], acc[mi][ni]);                           \
  PH_END();                                                                    \
  /* ph4: hi*lo mf4-7 */                                                       \
  PH_TOP();                                                                    \
  if (STAGE) STG2((u) + 1, nbuf, 1);                                           \
  PH_MID();                                                                    \
  _Pragma("unroll") for (int mi = 0; mi < 4; ++mi)                             \
  _Pragma("unroll") for (int ni = 0; ni < 4; ++ni)                             \
    acc[4 + mi][ni] = MF(ahi[4 + mi], blo[ni], acc[4 + mi][ni]);               \
  PH_END();                                                                    \
  /* ph5: lo*hi mf0-3 */                                                       \
  WV5; PH_TOP();                                                               \
  _Pragma("unroll") for (int q = 0; q < 4; ++q) alo[q] = ds128(vA + 16384 + q * 1024); \
  PH_MID();                                                                    \
  _Pragma("unroll") for (int mi = 0; mi < 4; ++mi)                             \
  _Pragma("unroll") for (int ni = 0; ni < 4; ++ni)                             \
    acc[mi][ni] = MF(alo[mi], bhi[ni], acc[mi][ni]);                           \
  PH_END();                                                                    \
  /* ph6: lo*hi mf4-7 */                                                       \
  PH_TOP();                                                                    \
  _Pragma("unroll") for (int q = 0; q < 4; ++q) alo[q] = ds128(vA + 16384 + (4 + q) * 1024); \
  PH_MID();                                                                    \
  _Pragma("unroll") for (int mi = 0; mi < 4; ++mi)                             \
  _Pragma("unroll") for (int ni = 0; ni < 4; ++ni)                             \
    acc[4 + mi][ni] = MF(alo[mi], bhi[ni], acc[4 + mi][ni]);                   \
  PH_END();                                                                    \
  vA ^= 65536u; vB ^= 65536u;                                                  \
} while (0)

  STG2(0, 0, 0); STG2(0, 0, 2); STG2(0, 0, 3); STG2(0, 0, 1);

  unsigned nbuf = 65536u;
  for (int u = 0; u < nkt - 1; ++u) {
    TILE(u, WAITV(4), WAITV(6), WAITV(8), 1);
    nbuf ^= 65536u;
  }
  TILE(nkt - 1, WAITV(4), WAITV(2), WAITV(0), 0);
#undef TILE
#undef PH_TOP
#undef PH_MID
#undef PH_END

  const size_t cb = (size_t)b * sC;
  const int mB = m0 + wm * 128 + ((lane >> 4) << 2);
  const int nB = n0 + wn * 64 + (lane & 15);
#pragma unroll
  for (int mf = 0; mf < 8; ++mf)
#pragma unroll
    for (int j = 0; j < 4; ++j) {
      int m = mB + mf * 16 + j;
#pragma unroll
      for (int nf = 0; nf < 4; ++nf) {
        int n = nB + nf * 16;
        float v = acc[mf][nf][j];
        size_t o = (size_t)m * N + n;
        if (EPI == 0) {
          v = (v + bias[n] + addend[o]) * scale;
          unsigned short hb = f2bf(v);
          outHi[o] = hb;
          outLo[o] = f2bf(v - bf2f(hb));
        } else {
          outF[cb + o] = v;
        }
      }
    }
}

// ====== split (hi/lo) GEMM, 128x128 tile, 256 threads, BK=32, 3 phases, 1-buffer 32KB ======
// Residency-optimized scores core (2 blocks/CU measured).
template <int EPI>
__global__ __launch_bounds__(256, 3) void k_split128(
    const unsigned short* __restrict__ Ah, const unsigned short* __restrict__ Al,
    const unsigned short* __restrict__ Bh, const unsigned short* __restrict__ Bl,
    int N, int K, long sA, long sB, long sC,
    const float* __restrict__ bias, const float* __restrict__ addend,
    float* __restrict__ outF, unsigned short* __restrict__ outHi,
    unsigned short* __restrict__ outLo, float scale, const int* __restrict__ npad) {
  extern __shared__ char lds[];
  const int tid = threadIdx.x, wave = tid >> 6, lane = tid & 63;
  int L = xcd_logical();
  const int n0 = (L % gridDim.x) * 128;
  int tmpL = L / gridDim.x;
  const int m0 = (tmpL % gridDim.y) * 128;
  const int b = tmpL / gridDim.y;
  if (npad && n0 >= npad[b]) return;
  const int wm = wave >> 1, wn = wave & 1;   // 2x2 waves; wave owns 64x64
  const unsigned short* gb[4];
  gb[0] = Ah + (size_t)b * sA + (size_t)m0 * K;
  gb[1] = Al + (size_t)b * sA + (size_t)m0 * K;
  gb[2] = Bh + (size_t)b * sB + (size_t)n0 * K;
  gb[3] = Bl + (size_t)b * sB + (size_t)n0 * K;
  const unsigned ldsB = ldsoff(lds);

  int soff[2];
#pragma unroll
  for (int s = 0; s < 2; ++s) {
    int l = swzi(s * 4096 + tid * 16);
    soff[s] = (l >> 6) * K + ((l >> 4) & 3) * 8;
  }
  const int aR = wm * 64 + (lane & 15);
  const int bR = wn * 64 + (lane & 15);
  const int kB = (lane >> 4) * 16;
  const int nkt = K >> 5;

  const unsigned vA = ldsB + (unsigned)swzi(aR * 64 + kB);          // Ah; Al = +8192
  const unsigned vB = ldsB + 16384u + (unsigned)swzi(bR * 64 + kB); // Bh; Bl = +8192

  f32x4 acc[4][4] = {};

  auto STG = [&](int t, int r) {   // region r, 2 units
    char* dst = lds + r * 8192 + tid * 16;
    const unsigned short* g = gb[r] + (size_t)t * 32;
    gload16(g + soff[0], dst);
    gload16(g + soff[1], dst + 4096);
  };

#define TILE3(u, WV1, WV2, WV3, STAGE) do {                                    \
  short8 ahi[4], bhi[4], blo[4], alo[4];                                       \
  /* ph1: hi*hi */                                                             \
  WV1; BAR();                                                                  \
  _Pragma("unroll") for (int q = 0; q < 4; ++q) bhi[q] = ds128(vB + q * 1024); \
  _Pragma("unroll") for (int q = 0; q < 4; ++q) ahi[q] = ds128(vA + q * 1024); \
  STG(u, 1);                                                                   \
  BAR(); WAITL(0); SCH0(); PRIO1();                                            \
  _Pragma("unroll") for (int mi = 0; mi < 4; ++mi)                             \
  _Pragma("unroll") for (int ni = 0; ni < 4; ++ni)                             \
    acc[mi][ni] = MF(ahi[mi], bhi[ni], acc[mi][ni]);                           \
  PRIO0(); SCH0();                                                             \
  /* ph2: hi*lo */                                                             \
  WV2; BAR();                                                                  \
  _Pragma("unroll") for (int q = 0; q < 4; ++q) blo[q] = ds128(vB + 8192 + q * 1024); \
  if (STAGE) { STG((u) + 1, 2); STG((u) + 1, 0); }                             \
  BAR(); WAITL(0); SCH0(); PRIO1();                                            \
  _Pragma("unroll") for (int mi = 0; mi < 4; ++mi)                             \
  _Pragma("unroll") for (int ni = 0; ni < 4; ++ni)                             \
    acc[mi][ni] = MF(ahi[mi], blo[ni], acc[mi][ni]);                           \
  PRIO0(); SCH0();                                                             \
  /* ph3: lo*hi */                                                             \
  WV3; BAR();                                                                  \
  _Pragma("unroll") for (int q = 0; q < 4; ++q) alo[q] = ds128(vA + 8192 + q * 1024); \
  if (STAGE) STG((u) + 1, 3);                                                  \
  BAR(); WAITL(0); SCH0(); PRIO1();                                            \
  _Pragma("unroll") for (int mi = 0; mi < 4; ++mi)                             \
  _Pragma("unroll") for (int ni = 0; ni < 4; ++ni)                             \
    acc[mi][ni] = MF(alo[mi], bhi[ni], acc[mi][ni]);                           \
  PRIO0(); SCH0();                                                             \
} while (0)

  // prologue: Bh[0], Ah[0], Bl[0] (2 units each -> 6 outstanding)
  STG(0, 2); STG(0, 0); STG(0, 3);

  for (int u = 0; u < nkt - 1; ++u)
    TILE3(u, WAITV(2), WAITV(2), WAITV(4), 1);
  TILE3(nkt - 1, WAITV(2), WAITV(2), WAITV(0), 0);
#undef TILE3

  const size_t cb = (size_t)b * sC;
  const int mB = m0 + wm * 64 + ((lane >> 4) << 2);
  const int nB = n0 + wn * 64 + (lane & 15);
#pragma unroll
  for (int mf = 0; mf < 4; ++mf)
#pragma unroll
    for (int j = 0; j < 4; ++j) {
      int m = mB + mf * 16 + j;
#pragma unroll
      for (int nf = 0; nf < 4; ++nf) {
        int n = nB + nf * 16;
        float v = acc[mf][nf][j];
        size_t o = (size_t)m * N + n;
        if (EPI == 0) {
          v = (v + bias[n] + addend[o]) * scale;
          unsigned short hb = f2bf(v);
          outHi[o] = hb;
          outLo[o] = f2bf(v - bf2f(hb));
        } else {
          outF[cb + o] = v;
        }
      }
    }
}

// -------- softmax: compact scores row -> full f32 attn row + compact bf16 attn --------
__global__ __launch_bounds__(256) void k_softmax(const float* __restrict__ scores_c,
    float* __restrict__ attn, unsigned short* __restrict__ attn_bc,
    const int* __restrict__ mask, const int* __restrict__ pfx,
    const int* __restrict__ cnt, const int* __restrict__ kpad) {
  __shared__ float sl[NMAX];
  __shared__ float red[8];
  long r = blockIdx.x;
  int b = (int)(r >> 11);
  int t = threadIdx.x;
  int cb = cnt[b], kp = kpad[b];
  const float* srow = scores_c + r * (long)NMAX;
  for (int i = t; i < cb; i += 256) sl[i] = srow[i];
  __syncthreads();
  int base = t * 8;
  const int* mrow = mask + (size_t)b * SS;
  int4 m0i = *(const int4*)(mrow + base);
  int4 m1i = *(const int4*)(mrow + base + 4);
  int mm[8] = {m0i.x, m0i.y, m0i.z, m0i.w, m1i.x, m1i.y, m1i.z, m1i.w};
  const int* prow = pfx + (size_t)b * SS;
  int4 p0i = *(const int4*)(prow + base);
  int4 p1i = *(const int4*)(prow + base + 4);
  int pp[8] = {p0i.x, p0i.y, p0i.z, p0i.w, p1i.x, p1i.y, p1i.z, p1i.w};
  float v[8];
#pragma unroll
  for (int j = 0; j < 8; ++j) v[j] = mm[j] ? -INFINITY : sl[pp[j]];
  float mx = v[0];
#pragma unroll
  for (int j = 1; j < 8; ++j) mx = fmaxf(mx, v[j]);
#pragma unroll
  for (int off = 32; off; off >>= 1) mx = fmaxf(mx, __shfl_xor(mx, off));
  int wv = t >> 6, ln = t & 63;
  if (ln == 0) red[wv] = mx;
  __syncthreads();
  mx = fmaxf(fmaxf(red[0], red[1]), fmaxf(red[2], red[3]));
  float sum = 0.f;
#pragma unroll
  for (int j = 0; j < 8; ++j) { v[j] = __expf(v[j] - mx); sum += v[j]; }
#pragma unroll
  for (int off = 32; off; off >>= 1) sum += __shfl_xor(sum, off);
  if (ln == 0) red[4 + wv] = sum;
  __syncthreads();
  sum = (red[4] + red[5]) + (red[6] + red[7]);
  float inv = 1.0f / sum;
#pragma unroll
  for (int j = 0; j < 8; ++j) v[j] *= inv;
  float* arow = attn + r * (long)SS;
  float4 w0; w0.x = v[0]; w0.y = v[1]; w0.z = v[2]; w0.w = v[3];
  float4 w1; w1.x = v[4]; w1.y = v[5]; w1.z = v[6]; w1.w = v[7];
  *(float4*)(arow + base) = w0;
  *(float4*)(arow + base + 4) = w1;
  __syncthreads();          // sl reads done; reuse for compact attn
#pragma unroll
  for (int j = 0; j < 8; ++j) if (!mm[j]) sl[pp[j]] = v[j];
  __syncthreads();
  unsigned short* brow = attn_bc + r * (long)NMAX;
  for (int i = t; i < kp; i += 256) brow[i] = f2bf(i < cb ? sl[i] : 0.f);
}

extern "C" void kernel_launch(void* const* d_in, const int* in_sizes, int n_in,
                              void* d_out, int out_size, void* d_ws, size_t ws_size,
                              hipStream_t stream) {
  (void)in_sizes; (void)n_in; (void)out_size; (void)ws_size;
  const float* x     = (const float*)d_in[0];
  const float* tgt   = (const float*)d_in[1];
  const float* enca  = (const float*)d_in[2];
  const float* encb  = (const float*)d_in[3];
  const int*   mask  = (const int*)d_in[4];
  const float* w_in  = (const float*)d_in[5];
  const float* b_in  = (const float*)d_in[6];
  const float* w_out = (const float*)d_in[7];
  const float* b_out = (const float*)d_in[8];

  float* out  = (float*)d_out;                       // [B,T,C]
  float* attn = out + (size_t)NB * TT * CC;          // [B,T,S]

  char* ws = (char*)d_ws;
  // liveness-phased layout (NMAX=1280)
  float*          scores_c = (float*)(ws + 0);                    // [0, 83886080)
  unsigned short* x_hi   = (unsigned short*)(ws + 0);             // dead before scores
  unsigned short* x_lo   = (unsigned short*)(ws + 33554432L);
  unsigned short* pv     = (unsigned short*)(ws + 0);             // after softmax
  unsigned short* h_hi   = (unsigned short*)(ws + 83886080L);
  unsigned short* h_lo   = (unsigned short*)(ws + 117440512L);
  unsigned short* attn_bc= (unsigned short*)(ws + 83886080L);     // after scores (h dead)
  unsigned short* a_tc_hi= (unsigned short*)(ws + 150994944L);
  unsigned short* a_tc_lo= (unsigned short*)(ws + 171966464L);
  unsigned short* b_tc   = (unsigned short*)(ws + 192937984L);
  unsigned short* w_in_hi= (unsigned short*)(ws + 213909504L);
  unsigned short* w_in_lo= (unsigned short*)(ws + 216006656L);
  unsigned short* w_out_b= (unsigned short*)(ws + 218103808L);
  int* idx  = (int*)(ws + 220200960L);
  int* pfx  = (int*)(ws + 220266496L);
  int* cnt  = (int*)(ws + 220332032L);
  int* kpad = (int*)(ws + 220332096L);

  hipFuncSetAttribute(reinterpret_cast<const void*>(&k_gemm8<2>),
                      hipFuncAttributeMaxDynamicSharedMemorySize, 131072);
  hipFuncSetAttribute(reinterpret_cast<const void*>(&k_gemm8<3>),
                      hipFuncAttributeMaxDynamicSharedMemorySize, 131072);
  hipFuncSetAttribute(reinterpret_cast<const void*>(&k_split6<0>),
                      hipFuncAttributeMaxDynamicSharedMemorySize, 131072);
  hipFuncSetAttribute(reinterpret_cast<const void*>(&k_split128<1>),
                      hipFuncAttributeMaxDynamicSharedMemorySize, 32768);

  dim3 blk(256), blk512(512);
  const float S05 = 0.70710678118654752f;

  k_scan<<<NB, blk, 0, stream>>>(mask, idx, pfx, cnt, kpad);
  k_split<<<2048, blk, 0, stream>>>(x, x_hi, x_lo, (long)NB * TT * CC / 4);
  k_split<<<512, blk, 0, stream>>>(w_in, w_in_hi, w_in_lo, (long)EE * CC / 4);
  k_conv<<<512, blk, 0, stream>>>(w_out, w_out_b, (long)CC * EE / 4);
  k_ta<<<dim3(SS / 64, EE / 64, NB), blk, 0, stream>>>(enca, mask, pfx, a_tc_hi, a_tc_lo);
  k_tb<<<dim3(NMAX / 64, EE / 64, NB), blk, 0, stream>>>(encb, idx, cnt, b_tc);

  // GEMM1: h = (x @ w_in^T + b_in + tgt) * sqrt(0.5). 6-phase 256^2 core, 256 blocks.
  k_split6<0><<<dim3(EE / 256, (NB * TT) / 256, 1), blk512, 131072, stream>>>(
      x_hi, x_lo, w_in_hi, w_in_lo, EE, CC, 0, 0, 0,
      b_in, tgt, nullptr, h_hi, h_lo, S05, nullptr);

  // scores_c = h @ a_tc (compact, batched). 128x128 core, 1280 blocks, early-exit.
  k_split128<1><<<dim3(NMAX / 128, TT / 128, NB), blk, 32768, stream>>>(
      h_hi, h_lo, a_tc_hi, a_tc_lo, NMAX, EE,
      (long)TT * EE, (long)NMAX * EE, (long)TT * NMAX,
      nullptr, nullptr, scores_c, nullptr, nullptr, 1.0f, kpad);

  // masked softmax on compact domain; writes full attn (f32) + compact attn_bc (bf16)
  k_softmax<<<NB * TT, blk, 0, stream>>>(scores_c, attn, attn_bc, mask, pfx, cnt, kpad);

  // pv = (attn_bc @ b_tc) * sqrt(S), dynamic K = kpad[b], bf16 out
  k_gemm8<2><<<dim3(EE / 256, TT / 256, NB), blk512, 131072, stream>>>(
      attn_bc, b_tc, EE, NMAX, kpad,
      (long)TT * NMAX, (long)EE * NMAX, (long)TT * EE,
      nullptr, nullptr, nullptr, pv, 45.254833995939045f);

  // out = (pv @ w_out^T + b_out + x) * sqrt(0.5)
  k_gemm8<3><<<dim3(CC / 256, (NB * TT) / 256, 1), blk512, 131072, stream>>>(
      pv, w_out_b, CC, EE, nullptr, 0, 0, 0,
      b_out, x, out, nullptr, S05);
}

// Round 17
// 458.103 us; speedup vs baseline: 1.0820x; 1.0041x over previous
//
#include <hip/hip_runtime.h>
#include <hip/hip_bf16.h>
#include <math.h>

#define NB 8
#define TT 2048
#define SS 2048
#define CC 1024
#define EE 1024
#define NMAX 1280

typedef __attribute__((ext_vector_type(8))) short short8;
typedef __attribute__((ext_vector_type(4))) float f32x4;

__device__ __forceinline__ unsigned short f2bf(float f) {
  unsigned u = __builtin_bit_cast(unsigned, f);
  u += 0x7fffu + ((u >> 16) & 1u);          // RNE
  return (unsigned short)(u >> 16);
}
__device__ __forceinline__ float bf2f(unsigned short h) {
  unsigned u = ((unsigned)h) << 16;
  return __builtin_bit_cast(float, u);
}
__device__ __forceinline__ void gload16(const void* g, void* l) {
  __builtin_amdgcn_global_load_lds((const __attribute__((address_space(1))) void*)g,
                                   (__attribute__((address_space(3))) void*)l, 16, 0, 0);
}
__device__ __forceinline__ unsigned ldsoff(const void* p) {
  return (unsigned)(size_t)(const __attribute__((address_space(3))) char*)p;
}
__device__ __forceinline__ short8 ds128(unsigned off) {
  short8 r;
  asm volatile("ds_read_b128 %0, %1" : "=v"(r) : "v"(off));
  return r;
}
// XOR swizzle: bits 4-6 ^= bits 7-9 (involution)
__device__ __forceinline__ int swzi(int x) { return x ^ (((x >> 7) & 7) << 4); }

#define WAITV(N) asm volatile("s_waitcnt vmcnt(" #N ")" ::: "memory")
#define WAITL(N) asm volatile("s_waitcnt lgkmcnt(" #N ")" ::: "memory")
#define BAR() __builtin_amdgcn_s_barrier()
#define SCH0() __builtin_amdgcn_sched_barrier(0)
#define PRIO1() __builtin_amdgcn_s_setprio(1)
#define PRIO0() __builtin_amdgcn_s_setprio(0)
#define MF(a_, b_, c_) __builtin_amdgcn_mfma_f32_16x16x32_bf16(a_, b_, c_, 0, 0, 0)

// chunked bijective XCD swizzle (requires nwg % 8 == 0; all our grids qualify)
__device__ __forceinline__ int xcd_logical() {
  int gx = gridDim.x, gy = gridDim.y, gz = gridDim.z;
  int pid = blockIdx.x + gx * (blockIdx.y + gy * blockIdx.z);
  int q = (gx * gy * gz) >> 3;
  return (pid & 7) * q + (pid >> 3);
}

// ---------------- mask scan: per batch, compaction tables ----------------
__global__ __launch_bounds__(256) void k_scan(const int* __restrict__ mask,
    int* __restrict__ idx, int* __restrict__ pfx, int* __restrict__ cnt,
    int* __restrict__ kpad) {
  __shared__ int cs[256];
  int b = blockIdx.x, t = threadIdx.x;
  const int* mrow = mask + (size_t)b * SS;
  int4 a = ((const int4*)mrow)[t * 2];
  int4 c2 = ((const int4*)mrow)[t * 2 + 1];
  int mm[8] = {a.x, a.y, a.z, a.w, c2.x, c2.y, c2.z, c2.w};
  int c = 0;
#pragma unroll
  for (int j = 0; j < 8; ++j) c += (mm[j] == 0);
  cs[t] = c;
  __syncthreads();
  if (t == 0) {
    int run = 0;
    for (int i = 0; i < 256; ++i) { int tmp = cs[i]; cs[i] = run; run += tmp; }
    cnt[b] = run;
    int kp = (run + 127) & ~127;
    if (kp > NMAX) kp = NMAX;
    kpad[b] = kp;
  }
  __syncthreads();
  int base = cs[t];
#pragma unroll
  for (int j = 0; j < 8; ++j) {
    int s = t * 8 + j;
    pfx[(size_t)b * SS + s] = base;
    if (mm[j] == 0) { idx[(size_t)b * SS + base] = s; base++; }
  }
}

// ------- fused format preps: x split (8.4M f4), w_in split (256K f4), w_out conv (256K f4) ----
__global__ __launch_bounds__(256) void k_prep(const float* __restrict__ x,
    unsigned short* __restrict__ x_hi, unsigned short* __restrict__ x_lo,
    const float* __restrict__ w_in,
    unsigned short* __restrict__ wi_hi, unsigned short* __restrict__ wi_lo,
    const float* __restrict__ w_out, unsigned short* __restrict__ wo_b) {
  const long NX = (long)NB * TT * CC / 4;   // 4194304
  const long NW = (long)EE * CC / 4;        // 262144
  long i = (long)blockIdx.x * blockDim.x + threadIdx.x;
  long stride = (long)gridDim.x * blockDim.x;
  for (; i < NX + 2 * NW; i += stride) {
    if (i < NX + NW) {
      const float* in = (i < NX) ? x : w_in;
      unsigned short* hi = (i < NX) ? x_hi : wi_hi;
      unsigned short* lo = (i < NX) ? x_lo : wi_lo;
      long k = (i < NX) ? i : (i - NX);
      float4 v = ((const float4*)in)[k];
      float f[4] = {v.x, v.y, v.z, v.w};
      unsigned short hh[4], ll[4];
#pragma unroll
      for (int j = 0; j < 4; ++j) {
        hh[j] = f2bf(f[j]);
        ll[j] = f2bf(f[j] - bf2f(hh[j]));
      }
      ushort4 h; h.x = hh[0]; h.y = hh[1]; h.z = hh[2]; h.w = hh[3];
      ushort4 l; l.x = ll[0]; l.y = ll[1]; l.z = ll[2]; l.w = ll[3];
      ((ushort4*)hi)[k] = h;
      ((ushort4*)lo)[k] = l;
    } else {
      long k = i - NX - NW;
      float4 v = ((const float4*)w_out)[k];
      ushort4 h; h.x = f2bf(v.x); h.y = f2bf(v.y); h.z = f2bf(v.z); h.w = f2bf(v.w);
      ((ushort4*)wo_b)[k] = h;
    }
  }
}

// ------- enc_a compact transpose, coalesced-read version -------
// Reads contiguous [64e x 64s] tiles (float4 along s); scatters on the WRITE side:
// unmasked s -> compact row pfx[s]. Padded rows [cnt,kpad) are NOT written (scores
// columns n>=cnt are never read by softmax; attn_bc zero-pad happens in k_softmax).
__global__ __launch_bounds__(256) void k_ta(const float* __restrict__ enca,
    const int* __restrict__ mask, const int* __restrict__ pfx,
    unsigned short* __restrict__ hi, unsigned short* __restrict__ lo) {
  __shared__ float tile[64][65];
  int b = blockIdx.z, s0 = blockIdx.x * 64, e0 = blockIdx.y * 64;
  const float* src = enca + (size_t)b * EE * SS;
  int t = threadIdx.x;
  int er = t >> 4;             // 0..15
  int slc = (t & 15) * 4;      // 0..60
#pragma unroll
  for (int i = 0; i < 4; ++i) {
    int e = er + i * 16;
    float4 v = *(const float4*)(src + (size_t)(e0 + e) * SS + s0 + slc);
    tile[e][slc] = v.x; tile[e][slc + 1] = v.y;
    tile[e][slc + 2] = v.z; tile[e][slc + 3] = v.w;
  }
  __syncthreads();
  int sl = t >> 2;             // 0..63
  int eq = (t & 3) * 16;       // 0,16,32,48
  int s = s0 + sl;
  if (mask[(size_t)b * SS + s] == 0) {
    int sc = pfx[(size_t)b * SS + s];
    size_t rb = (size_t)b * NMAX * EE + (size_t)sc * EE + e0 + eq;
#pragma unroll
    for (int i = 0; i < 4; ++i) {
      unsigned short hh[4], ll[4];
#pragma unroll
      for (int j = 0; j < 4; ++j) {
        float f = tile[eq + i * 4 + j][sl];
        hh[j] = f2bf(f);
        ll[j] = f2bf(f - bf2f(hh[j]));
      }
      ushort4 h4; h4.x = hh[0]; h4.y = hh[1]; h4.z = hh[2]; h4.w = hh[3];
      ushort4 l4; l4.x = ll[0]; l4.y = ll[1]; l4.z = ll[2]; l4.w = ll[3];
      *(ushort4*)(hi + rb + i * 4) = h4;
      *(ushort4*)(lo + rb + i * 4) = l4;
    }
  }
}

// ------- enc_b compact transpose: b_tc[b][e][sc] = enc_b[b][idx[sc]][e], bf16 -------
__global__ __launch_bounds__(256) void k_tb(const float* __restrict__ encb,
    const int* __restrict__ idx, const int* __restrict__ cnt,
    unsigned short* __restrict__ out) {
  __shared__ float tile[64][65];
  int b = blockIdx.z, sc0 = blockIdx.x * 64, e0 = blockIdx.y * 64;
  int cb = cnt[b];
  const float* src = encb + (size_t)b * SS * EE;
  int t = threadIdx.x, tr = t >> 4, tc = (t & 15) * 4;
#pragma unroll
  for (int i = 0; i < 4; ++i) {
    int r = tr + i * 16;   // sc-local
    int sc = sc0 + r;
    int sidx = (sc < cb) ? idx[(size_t)b * SS + sc] : -1;
    float4 v;
    if (sidx >= 0) v = *(const float4*)(src + (size_t)sidx * EE + e0 + tc);
    else { v.x = v.y = v.z = v.w = 0.f; }
    tile[r][tc] = v.x; tile[r][tc + 1] = v.y; tile[r][tc + 2] = v.z; tile[r][tc + 3] = v.w;
  }
  __syncthreads();
  size_t ob = (size_t)b * EE * NMAX;
#pragma unroll
  for (int i = 0; i < 4; ++i) {
    int c = tr + i * 16;   // e-local
    unsigned short hh[4];
#pragma unroll
    for (int j = 0; j < 4; ++j) hh[j] = f2bf(tile[tc + j][c]);
    ushort4 h; h.x = hh[0]; h.y = hh[1]; h.z = hh[2]; h.w = hh[3];
    *(ushort4*)(out + ob + (size_t)(e0 + c) * NMAX + sc0 + tc) = h;
  }
}

// ================= plain bf16 GEMM, 256x256 tile, BK=64, 4 phases, dynamic K ==============
template <int EPI>
__global__ __launch_bounds__(512, 2) void k_gemm8(
    const unsigned short* __restrict__ A, const unsigned short* __restrict__ B,
    int N, int KROW, const int* __restrict__ kdyn, long sA, long sB, long sC,
    const float* __restrict__ bias, const float* __restrict__ addend,
    float* __restrict__ outF, unsigned short* __restrict__ outH, float scale) {
  extern __shared__ char lds[];
  const int tid = threadIdx.x, wave = tid >> 6, lane = tid & 63;
  int L = xcd_logical();
  const int n0 = (L % gridDim.x) * 256;
  int tmpL = L / gridDim.x;
  const int m0 = (tmpL % gridDim.y) * 256;
  const int b = tmpL / gridDim.y;
  const int KD = kdyn ? kdyn[b] : KROW;
  const int wm = wave >> 2, wn = wave & 3;
  const unsigned short* gA = A + (size_t)b * sA + (size_t)m0 * KROW;
  const unsigned short* gB = B + (size_t)b * sB + (size_t)n0 * KROW;
  const unsigned ldsB = ldsoff(lds);

  int srow[2], sk8[2];
#pragma unroll
  for (int s = 0; s < 2; ++s) {
    int l = swzi((s * 512 + tid) * 16);
    srow[s] = l >> 6;
    sk8[s] = (l >> 4) & 3;
  }
  const int aR = wm * 128 + (lane & 15);
  const int bR = wn * 64 + (lane & 15);
  const int kB = (lane >> 4) * 16;
  const int nkt = KD >> 6;

  f32x4 acc[8][4] = {};

  auto STG = [&](int t, int tensor, int ks) {
    const unsigned short* g = tensor ? gB : gA;
    char* dst = lds + (t & 1) * 65536 + tensor * 32768 + ks * 16384 + wave * 1024;
    size_t gk = (size_t)t * 64 + ks * 32;
#pragma unroll
    for (int s = 0; s < 2; ++s)
      gload16(g + ((size_t)srow[s] * KROW + gk + sk8[s] * 8), dst + s * 8192);
  };
  auto RA = [&](int t, int ks, int mf) {
    int lin = (aR + mf * 16) * 64 + kB;
    return ds128(ldsB + (t & 1) * 65536 + ks * 16384 + swzi(lin));
  };
  auto RB = [&](int t, int ks, int nf) {
    int lin = (bR + nf * 16) * 64 + kB;
    return ds128(ldsB + (t & 1) * 65536 + 32768 + ks * 16384 + swzi(lin));
  };

  STG(0, 1, 0); STG(0, 0, 0); STG(0, 0, 1); STG(0, 1, 1);
  if (nkt > 1) { STG(1, 1, 0); STG(1, 0, 0); }

  for (int u = 0; u < nkt; ++u) {
    if (u + 1 < nkt) { WAITV(8); } else { WAITV(0); }
    BAR();
    short8 bf[4], af[4];
#pragma unroll
    for (int nf = 0; nf < 4; ++nf) bf[nf] = RB(u, 0, nf);
#pragma unroll
    for (int mf = 0; mf < 4; ++mf) af[mf] = RA(u, 0, mf);
    if (u + 1 < nkt) { STG(u + 1, 0, 1); STG(u + 1, 1, 1); }
    BAR(); WAITL(0); SCH0(); PRIO1();
#pragma unroll
    for (int mf = 0; mf < 4; ++mf)
#pragma unroll
      for (int nf = 0; nf < 4; ++nf) acc[mf][nf] = MF(af[mf], bf[nf], acc[mf][nf]);
    PRIO0(); SCH0(); BAR();
#pragma unroll
    for (int mf = 0; mf < 4; ++mf) af[mf] = RA(u, 0, mf + 4);
    if (u + 2 < nkt) STG(u + 2, 1, 0);
    BAR(); WAITL(0); SCH0(); PRIO1();
#pragma unroll
    for (int mf = 0; mf < 4; ++mf)
#pragma unroll
      for (int nf = 0; nf < 4; ++nf) acc[mf + 4][nf] = MF(af[mf], bf[nf], acc[mf + 4][nf]);
    PRIO0(); SCH0();
    if (u + 2 < nkt) { WAITV(10); } else if (u + 1 < nkt) { WAITV(8); } else { WAITV(0); }
    BAR();
#pragma unroll
    for (int nf = 0; nf < 4; ++nf) bf[nf] = RB(u, 1, nf);
#pragma unroll
    for (int mf = 0; mf < 4; ++mf) af[mf] = RA(u, 1, mf);
    if (u + 2 < nkt) STG(u + 2, 0, 0);
    BAR(); WAITL(0); SCH0(); PRIO1();
#pragma unroll
    for (int mf = 0; mf < 4; ++mf)
#pragma unroll
      for (int nf = 0; nf < 4; ++nf) acc[mf][nf] = MF(af[mf], bf[nf], acc[mf][nf]);
    PRIO0(); SCH0(); BAR();
#pragma unroll
    for (int mf = 0; mf < 4; ++mf) af[mf] = RA(u, 1, mf + 4);
    BAR(); WAITL(0); SCH0(); PRIO1();
#pragma unroll
    for (int mf = 0; mf < 4; ++mf)
#pragma unroll
      for (int nf = 0; nf < 4; ++nf) acc[mf + 4][nf] = MF(af[mf], bf[nf], acc[mf + 4][nf]);
    PRIO0(); SCH0(); BAR();
  }

  const size_t cb = (size_t)b * sC;
  const int mB = m0 + wm * 128 + ((lane >> 4) << 2);
  const int nB = n0 + wn * 64 + (lane & 15);
#pragma unroll
  for (int mf = 0; mf < 8; ++mf)
#pragma unroll
    for (int j = 0; j < 4; ++j) {
      int m = mB + mf * 16 + j;
#pragma unroll
      for (int nf = 0; nf < 4; ++nf) {
        int n = nB + nf * 16;
        float v = acc[mf][nf][j];
        size_t o = (size_t)m * N + n;
        if (EPI == 2) outH[cb + o] = f2bf(v * scale);
        else outF[o] = (v + bias[n] + addend[o]) * scale;
      }
    }
}

// ============ split (hi/lo) GEMM, 256x256 tile, BK=32, 3 products, 6 sub-phases ============
// R5/R9-proven schedule, double-buffered 128KB. Used for GEMM1.
template <int EPI>
__global__ __launch_bounds__(512, 2) void k_split6(
    const unsigned short* __restrict__ Ah, const unsigned short* __restrict__ Al,
    const unsigned short* __restrict__ Bh, const unsigned short* __restrict__ Bl,
    int N, int K, long sA, long sB, long sC,
    const float* __restrict__ bias, const float* __restrict__ addend,
    float* __restrict__ outF, unsigned short* __restrict__ outHi,
    unsigned short* __restrict__ outLo, float scale, const int* __restrict__ npad) {
  extern __shared__ char lds[];
  const int tid = threadIdx.x, wave = tid >> 6, lane = tid & 63;
  int L = xcd_logical();
  const int n0 = (L % gridDim.x) * 256;
  int tmpL = L / gridDim.x;
  const int m0 = (tmpL % gridDim.y) * 256;
  const int b = tmpL / gridDim.y;
  if (npad && n0 >= npad[b]) return;
  const int wm = wave >> 2, wn = wave & 3;
  const unsigned short* gb[4];
  gb[0] = Ah + (size_t)b * sA + (size_t)m0 * K;
  gb[1] = Al + (size_t)b * sA + (size_t)m0 * K;
  gb[2] = Bh + (size_t)b * sB + (size_t)n0 * K;
  gb[3] = Bl + (size_t)b * sB + (size_t)n0 * K;
  const unsigned ldsB = ldsoff(lds);

  int soff[2];
#pragma unroll
  for (int s = 0; s < 2; ++s) {
    int l = swzi((s * 512 + tid) * 16);
    soff[s] = (l >> 6) * K + ((l >> 4) & 3) * 8;
  }
  const int aR = wm * 128 + (lane & 15);
  const int bR = wn * 64 + (lane & 15);
  const int kB = (lane >> 4) * 16;
  const int nkt = K >> 5;

  unsigned vA = ldsB + (unsigned)swzi(aR * 64 + kB);
  unsigned vB = ldsB + (unsigned)swzi(bR * 64 + kB);

  f32x4 acc[8][4] = {};

  auto STG2 = [&](int t, unsigned bufbase, int region) {
    char* dst = lds + bufbase + region * 16384 + tid * 16;
    const unsigned short* g = gb[region] + (size_t)t * 32;
#pragma unroll
    for (int s = 0; s < 2; ++s)
      gload16(g + soff[s], dst + s * 8192);
  };

#define PH_TOP() BAR()
#define PH_MID() BAR(); WAITL(0); SCH0(); PRIO1()
#define PH_END() PRIO0(); SCH0()

#define TILE(u, WV1, WV3, WV5, STAGE) do {                                     \
  short8 ahi[8], bhi[4], blo[4], alo[4];                                       \
  /* ph1: hi*hi mf0-3 */                                                       \
  WV1; PH_TOP();                                                               \
  _Pragma("unroll") for (int q = 0; q < 4; ++q) bhi[q] = ds128(vB + 32768 + q * 1024); \
  _Pragma("unroll") for (int q = 0; q < 4; ++q) ahi[q] = ds128(vA + q * 1024); \
  if (STAGE) STG2((u) + 1, nbuf, 0);                                           \
  PH_MID();                                                                    \
  _Pragma("unroll") for (int mi = 0; mi < 4; ++mi)                             \
  _Pragma("unroll") for (int ni = 0; ni < 4; ++ni)                             \
    acc[mi][ni] = MF(ahi[mi], bhi[ni], acc[mi][ni]);                           \
  PH_END();                                                                    \
  /* ph2: hi*hi mf4-7 */                                                       \
  PH_TOP();                                                                    \
  _Pragma("unroll") for (int q = 0; q < 4; ++q) ahi[4 + q] = ds128(vA + (4 + q) * 1024); \
  if (STAGE) STG2((u) + 1, nbuf, 2);                                           \
  PH_MID();                                                                    \
  _Pragma("unroll") for (int mi = 0; mi < 4; ++mi)                             \
  _Pragma("unroll") for (int ni = 0; ni < 4; ++ni)                             \
    acc[4 + mi][ni] = MF(ahi[4 + mi], bhi[ni], acc[4 + mi][ni]);               \
  PH_END();                                                                    \
  /* ph3: hi*lo mf0-3 */                                                       \
  WV3; PH_TOP();                                                               \
  _Pragma("unroll") for (int q = 0; q < 4; ++q) blo[q] = ds128(vB + 49152 + q * 1024); \
  if (STAGE) STG2((u) + 1, nbuf, 3);                                           \
  PH_MID();                                                                    \
  _Pragma("unroll") for (int mi = 0; mi < 4; ++mi)                             \
  _Pragma("unroll") for (int ni = 0; ni < 4; ++ni)                             \
    acc[mi][ni] = MF(ahi[mi], blo[ni], acc[mi][ni]);                           \
  PH_END();                                                                    \
  /* ph4: hi*lo mf4-7 */                                                       \
  PH_TOP();                                                                    \
  if (STAGE) STG2((u) + 1, nbuf, 1);                                           \
  PH_MID();                                                                    \
  _Pragma("unroll") for (int mi = 0; mi < 4; ++mi)                             \
  _Pragma("unroll") for (int ni = 0; ni < 4; ++ni)                             \
    acc[4 + mi][ni] = MF(ahi[4 + mi], blo[ni], acc[4 + mi][ni]);               \
  PH_END();                                                                    \
  /* ph5: lo*hi mf0-3 */                                                       \
  WV5; PH_TOP();                                                               \
  _Pragma("unroll") for (int q = 0; q < 4; ++q) alo[q] = ds128(vA + 16384 + q * 1024); \
  PH_MID();                                                                    \
  _Pragma("unroll") for (int mi = 0; mi < 4; ++mi)                             \
  _Pragma("unroll") for (int ni = 0; ni < 4; ++ni)                             \
    acc[mi][ni] = MF(alo[mi], bhi[ni], acc[mi][ni]);                           \
  PH_END();                                                                    \
  /* ph6: lo*hi mf4-7 */                                                       \
  PH_TOP();                                                                    \
  _Pragma("unroll") for (int q = 0; q < 4; ++q) alo[q] = ds128(vA + 16384 + (4 + q) * 1024); \
  PH_MID();                                                                    \
  _Pragma("unroll") for (int mi = 0; mi < 4; ++mi)                             \
  _Pragma("unroll") for (int ni = 0; ni < 4; ++ni)                             \
    acc[4 + mi][ni] = MF(alo[mi], bhi[ni], acc[4 + mi][ni]);                   \
  PH_END();                                                                    \
  vA ^= 65536u; vB ^= 65536u;                                                  \
} while (0)

  STG2(0, 0, 0); STG2(0, 0, 2); STG2(0, 0, 3); STG2(0, 0, 1);

  unsigned nbuf = 65536u;
  for (int u = 0; u < nkt - 1; ++u) {
    TILE(u, WAITV(4), WAITV(6), WAITV(8), 1);
    nbuf ^= 65536u;
  }
  TILE(nkt - 1, WAITV(4), WAITV(2), WAITV(0), 0);
#undef TILE
#undef PH_TOP
#undef PH_MID
#undef PH_END

  const size_t cb = (size_t)b * sC;
  const int mB = m0 + wm * 128 + ((lane >> 4) << 2);
  const int nB = n0 + wn * 64 + (lane & 15);
#pragma unroll
  for (int mf = 0; mf < 8; ++mf)
#pragma unroll
    for (int j = 0; j < 4; ++j) {
      int m = mB + mf * 16 + j;
#pragma unroll
      for (int nf = 0; nf < 4; ++nf) {
        int n = nB + nf * 16;
        float v = acc[mf][nf][j];
        size_t o = (size_t)m * N + n;
        if (EPI == 0) {
          v = (v + bias[n] + addend[o]) * scale;
          unsigned short hb = f2bf(v);
          outHi[o] = hb;
          outLo[o] = f2bf(v - bf2f(hb));
        } else {
          outF[cb + o] = v;
        }
      }
    }
}

// ====== split (hi/lo) GEMM, 128x128 tile, 256 threads, BK=32, 3 phases, 1-buffer 32KB ======
// Residency-optimized scores core.
template <int EPI>
__global__ __launch_bounds__(256, 3) void k_split128(
    const unsigned short* __restrict__ Ah, const unsigned short* __restrict__ Al,
    const unsigned short* __restrict__ Bh, const unsigned short* __restrict__ Bl,
    int N, int K, long sA, long sB, long sC,
    const float* __restrict__ bias, const float* __restrict__ addend,
    float* __restrict__ outF, unsigned short* __restrict__ outHi,
    unsigned short* __restrict__ outLo, float scale, const int* __restrict__ npad) {
  extern __shared__ char lds[];
  const int tid = threadIdx.x, wave = tid >> 6, lane = tid & 63;
  int L = xcd_logical();
  const int n0 = (L % gridDim.x) * 128;
  int tmpL = L / gridDim.x;
  const int m0 = (tmpL % gridDim.y) * 128;
  const int b = tmpL / gridDim.y;
  if (npad && n0 >= npad[b]) return;
  const int wm = wave >> 1, wn = wave & 1;   // 2x2 waves; wave owns 64x64
  const unsigned short* gb[4];
  gb[0] = Ah + (size_t)b * sA + (size_t)m0 * K;
  gb[1] = Al + (size_t)b * sA + (size_t)m0 * K;
  gb[2] = Bh + (size_t)b * sB + (size_t)n0 * K;
  gb[3] = Bl + (size_t)b * sB + (size_t)n0 * K;
  const unsigned ldsB = ldsoff(lds);

  int soff[2];
#pragma unroll
  for (int s = 0; s < 2; ++s) {
    int l = swzi(s * 4096 + tid * 16);
    soff[s] = (l >> 6) * K + ((l >> 4) & 3) * 8;
  }
  const int aR = wm * 64 + (lane & 15);
  const int bR = wn * 64 + (lane & 15);
  const int kB = (lane >> 4) * 16;
  const int nkt = K >> 5;

  const unsigned vA = ldsB + (unsigned)swzi(aR * 64 + kB);          // Ah; Al = +8192
  const unsigned vB = ldsB + 16384u + (unsigned)swzi(bR * 64 + kB); // Bh; Bl = +8192

  f32x4 acc[4][4] = {};

  auto STG = [&](int t, int r) {   // region r, 2 units
    char* dst = lds + r * 8192 + tid * 16;
    const unsigned short* g = gb[r] + (size_t)t * 32;
    gload16(g + soff[0], dst);
    gload16(g + soff[1], dst + 4096);
  };

#define TILE3(u, WV1, WV2, WV3, STAGE) do {                                    \
  short8 ahi[4], bhi[4], blo[4], alo[4];                                       \
  /* ph1: hi*hi */                                                             \
  WV1; BAR();                                                                  \
  _Pragma("unroll") for (int q = 0; q < 4; ++q) bhi[q] = ds128(vB + q * 1024); \
  _Pragma("unroll") for (int q = 0; q < 4; ++q) ahi[q] = ds128(vA + q * 1024); \
  STG(u, 1);                                                                   \
  BAR(); WAITL(0); SCH0(); PRIO1();                                            \
  _Pragma("unroll") for (int mi = 0; mi < 4; ++mi)                             \
  _Pragma("unroll") for (int ni = 0; ni < 4; ++ni)                             \
    acc[mi][ni] = MF(ahi[mi], bhi[ni], acc[mi][ni]);                           \
  PRIO0(); SCH0();                                                             \
  /* ph2: hi*lo */                                                             \
  WV2; BAR();                                                                  \
  _Pragma("unroll") for (int q = 0; q < 4; ++q) blo[q] = ds128(vB + 8192 + q * 1024); \
  if (STAGE) { STG((u) + 1, 2); STG((u) + 1, 0); }                             \
  BAR(); WAITL(0); SCH0(); PRIO1();                                            \
  _Pragma("unroll") for (int mi = 0; mi < 4; ++mi)                             \
  _Pragma("unroll") for (int ni = 0; ni < 4; ++ni)                             \
    acc[mi][ni] = MF(ahi[mi], blo[ni], acc[mi][ni]);                           \
  PRIO0(); SCH0();                                                             \
  /* ph3: lo*hi */                                                             \
  WV3; BAR();                                                                  \
  _Pragma("unroll") for (int q = 0; q < 4; ++q) alo[q] = ds128(vA + 8192 + q * 1024); \
  if (STAGE) STG((u) + 1, 3);                                                  \
  BAR(); WAITL(0); SCH0(); PRIO1();                                            \
  _Pragma("unroll") for (int mi = 0; mi < 4; ++mi)                             \
  _Pragma("unroll") for (int ni = 0; ni < 4; ++ni)                             \
    acc[mi][ni] = MF(alo[mi], bhi[ni], acc[mi][ni]);                           \
  PRIO0(); SCH0();                                                             \
} while (0)

  // prologue: Bh[0], Ah[0], Bl[0] (2 units each -> 6 outstanding)
  STG(0, 2); STG(0, 0); STG(0, 3);

  for (int u = 0; u < nkt - 1; ++u)
    TILE3(u, WAITV(2), WAITV(2), WAITV(4), 1);
  TILE3(nkt - 1, WAITV(2), WAITV(2), WAITV(0), 0);
#undef TILE3

  const size_t cb = (size_t)b * sC;
  const int mB = m0 + wm * 64 + ((lane >> 4) << 2);
  const int nB = n0 + wn * 64 + (lane & 15);
#pragma unroll
  for (int mf = 0; mf < 4; ++mf)
#pragma unroll
    for (int j = 0; j < 4; ++j) {
      int m = mB + mf * 16 + j;
#pragma unroll
      for (int nf = 0; nf < 4; ++nf) {
        int n = nB + nf * 16;
        float v = acc[mf][nf][j];
        size_t o = (size_t)m * N + n;
        if (EPI == 0) {
          v = (v + bias[n] + addend[o]) * scale;
          unsigned short hb = f2bf(v);
          outHi[o] = hb;
          outLo[o] = f2bf(v - bf2f(hb));
        } else {
          outF[cb + o] = v;
        }
      }
    }
}

// -------- softmax: compact scores row -> full f32 attn row + compact bf16 attn --------
__global__ __launch_bounds__(256) void k_softmax(const float* __restrict__ scores_c,
    float* __restrict__ attn, unsigned short* __restrict__ attn_bc,
    const int* __restrict__ mask, const int* __restrict__ pfx,
    const int* __restrict__ cnt, const int* __restrict__ kpad) {
  __shared__ float sl[NMAX];
  __shared__ float red[8];
  long r = blockIdx.x;
  int b = (int)(r >> 11);
  int t = threadIdx.x;
  int cb = cnt[b], kp = kpad[b];
  const float* srow = scores_c + r * (long)NMAX;
  for (int i = t; i < cb; i += 256) sl[i] = srow[i];
  __syncthreads();
  int base = t * 8;
  const int* mrow = mask + (size_t)b * SS;
  int4 m0i = *(const int4*)(mrow + base);
  int4 m1i = *(const int4*)(mrow + base + 4);
  int mm[8] = {m0i.x, m0i.y, m0i.z, m0i.w, m1i.x, m1i.y, m1i.z, m1i.w};
  const int* prow = pfx + (size_t)b * SS;
  int4 p0i = *(const int4*)(prow + base);
  int4 p1i = *(const int4*)(prow + base + 4);
  int pp[8] = {p0i.x, p0i.y, p0i.z, p0i.w, p1i.x, p1i.y, p1i.z, p1i.w};
  float v[8];
#pragma unroll
  for (int j = 0; j < 8; ++j) v[j] = mm[j] ? -INFINITY : sl[pp[j]];
  float mx = v[0];
#pragma unroll
  for (int j = 1; j < 8; ++j) mx = fmaxf(mx, v[j]);
#pragma unroll
  for (int off = 32; off; off >>= 1) mx = fmaxf(mx, __shfl_xor(mx, off));
  int wv = t >> 6, ln = t & 63;
  if (ln == 0) red[wv] = mx;
  __syncthreads();
  mx = fmaxf(fmaxf(red[0], red[1]), fmaxf(red[2], red[3]));
  float sum = 0.f;
#pragma unroll
  for (int j = 0; j < 8; ++j) { v[j] = __expf(v[j] - mx); sum += v[j]; }
#pragma unroll
  for (int off = 32; off; off >>= 1) sum += __shfl_xor(sum, off);
  if (ln == 0) red[4 + wv] = sum;
  __syncthreads();
  sum = (red[4] + red[5]) + (red[6] + red[7]);
  float inv = 1.0f / sum;
#pragma unroll
  for (int j = 0; j < 8; ++j) v[j] *= inv;
  float* arow = attn + r * (long)SS;
  float4 w0; w0.x = v[0]; w0.y = v[1]; w0.z = v[2]; w0.w = v[3];
  float4 w1; w1.x = v[4]; w1.y = v[5]; w1.z = v[6]; w1.w = v[7];
  *(float4*)(arow + base) = w0;
  *(float4*)(arow + base + 4) = w1;
  __syncthreads();          // sl reads done; reuse for compact attn
#pragma unroll
  for (int j = 0; j < 8; ++j) if (!mm[j]) sl[pp[j]] = v[j];
  __syncthreads();
  unsigned short* brow = attn_bc + r * (long)NMAX;
  for (int i = t; i < kp; i += 256) brow[i] = f2bf(i < cb ? sl[i] : 0.f);
}

extern "C" void kernel_launch(void* const* d_in, const int* in_sizes, int n_in,
                              void* d_out, int out_size, void* d_ws, size_t ws_size,
                              hipStream_t stream) {
  (void)in_sizes; (void)n_in; (void)out_size; (void)ws_size;
  const float* x     = (const float*)d_in[0];
  const float* tgt   = (const float*)d_in[1];
  const float* enca  = (const float*)d_in[2];
  const float* encb  = (const float*)d_in[3];
  const int*   mask  = (const int*)d_in[4];
  const float* w_in  = (const float*)d_in[5];
  const float* b_in  = (const float*)d_in[6];
  const float* w_out = (const float*)d_in[7];
  const float* b_out = (const float*)d_in[8];

  float* out  = (float*)d_out;                       // [B,T,C]
  float* attn = out + (size_t)NB * TT * CC;          // [B,T,S]

  char* ws = (char*)d_ws;
  // liveness-phased layout (NMAX=1280)
  float*          scores_c = (float*)(ws + 0);                    // [0, 83886080)
  unsigned short* x_hi   = (unsigned short*)(ws + 0);             // dead before scores
  unsigned short* x_lo   = (unsigned short*)(ws + 33554432L);
  unsigned short* pv     = (unsigned short*)(ws + 0);             // after softmax
  unsigned short* h_hi   = (unsigned short*)(ws + 83886080L);
  unsigned short* h_lo   = (unsigned short*)(ws + 117440512L);
  unsigned short* attn_bc= (unsigned short*)(ws + 83886080L);     // after scores (h dead)
  unsigned short* a_tc_hi= (unsigned short*)(ws + 150994944L);
  unsigned short* a_tc_lo= (unsigned short*)(ws + 171966464L);
  unsigned short* b_tc   = (unsigned short*)(ws + 192937984L);
  unsigned short* w_in_hi= (unsigned short*)(ws + 213909504L);
  unsigned short* w_in_lo= (unsigned short*)(ws + 216006656L);
  unsigned short* w_out_b= (unsigned short*)(ws + 218103808L);
  int* idx  = (int*)(ws + 220200960L);
  int* pfx  = (int*)(ws + 220266496L);
  int* cnt  = (int*)(ws + 220332032L);
  int* kpad = (int*)(ws + 220332096L);

  hipFuncSetAttribute(reinterpret_cast<const void*>(&k_gemm8<2>),
                      hipFuncAttributeMaxDynamicSharedMemorySize, 131072);
  hipFuncSetAttribute(reinterpret_cast<const void*>(&k_gemm8<3>),
                      hipFuncAttributeMaxDynamicSharedMemorySize, 131072);
  hipFuncSetAttribute(reinterpret_cast<const void*>(&k_split6<0>),
                      hipFuncAttributeMaxDynamicSharedMemorySize, 131072);
  hipFuncSetAttribute(reinterpret_cast<const void*>(&k_split128<1>),
                      hipFuncAttributeMaxDynamicSharedMemorySize, 32768);

  dim3 blk(256), blk512(512);
  const float S05 = 0.70710678118654752f;

  k_scan<<<NB, blk, 0, stream>>>(mask, idx, pfx, cnt, kpad);
  // fused format preps (x split + w_in split + w_out conv), one launch
  k_prep<<<2048, blk, 0, stream>>>(x, x_hi, x_lo, w_in, w_in_hi, w_in_lo, w_out, w_out_b);

  // GEMM1: h = (x @ w_in^T + b_in + tgt) * sqrt(0.5). 6-phase 256^2 core, 256 blocks.
  k_split6<0><<<dim3(EE / 256, (NB * TT) / 256, 1), blk512, 131072, stream>>>(
      x_hi, x_lo, w_in_hi, w_in_lo, EE, CC, 0, 0, 0,
      b_in, tgt, nullptr, h_hi, h_lo, S05, nullptr);

  // compact transposes after GEMM1: a_tc/b_tc land L2/L3-warm for scores & PV
  k_ta<<<dim3(SS / 64, EE / 64, NB), blk, 0, stream>>>(enca, mask, pfx, a_tc_hi, a_tc_lo);
  k_tb<<<dim3(NMAX / 64, EE / 64, NB), blk, 0, stream>>>(encb, idx, cnt, b_tc);

  // scores_c = h @ a_tc (compact, batched). 128x128 core, 1280 blocks, early-exit.
  k_split128<1><<<dim3(NMAX / 128, TT / 128, NB), blk, 32768, stream>>>(
      h_hi, h_lo, a_tc_hi, a_tc_lo, NMAX, EE,
      (long)TT * EE, (long)NMAX * EE, (long)TT * NMAX,
      nullptr, nullptr, scores_c, nullptr, nullptr, 1.0f, kpad);

  // masked softmax on compact domain; writes full attn (f32) + compact attn_bc (bf16)
  k_softmax<<<NB * TT, blk, 0, stream>>>(scores_c, attn, attn_bc, mask, pfx, cnt, kpad);

  // pv = (attn_bc @ b_tc) * sqrt(S), dynamic K = kpad[b], bf16 out
  k_gemm8<2><<<dim3(EE / 256, TT / 256, NB), blk512, 131072, stream>>>(
      attn_bc, b_tc, EE, NMAX, kpad,
      (long)TT * NMAX, (long)EE * NMAX, (long)TT * EE,
      nullptr, nullptr, nullptr, pv, 45.254833995939045f);

  // out = (pv @ w_out^T + b_out + x) * sqrt(0.5)
  k_gemm8<3><<<dim3(CC / 256, (NB * TT) / 256, 1), blk512, 131072, stream>>>(
      pv, w_out_b, CC, EE, nullptr, 0, 0, 0,
      b_out, x, out, nullptr, S05);
}